// Round 1
// baseline (924.417 us; speedup 1.0000x reference)
//
#include <hip/hip_runtime.h>

constexpr int TPB = 256;

__device__ __forceinline__ int wave_incl_scan(int x, int lane) {
#pragma unroll
  for (int d = 1; d < 64; d <<= 1) {
    int y = __shfl_up(x, d);
    if (lane >= d) x += y;
  }
  return x;
}

__global__ void count_kernel(const int* __restrict__ col, int* __restrict__ cnt, int e) {
  int i = blockIdx.x * TPB + threadIdx.x;
  if (i < e) atomicAdd(&cnt[col[i]], 1);
}

__global__ void dinv_kernel(const int* __restrict__ cnt, float* __restrict__ dinv, int n) {
  int i = blockIdx.x * TPB + threadIdx.x;
  if (i < n) dinv[i] = rsqrtf(1.0f + (float)cnt[i]);  // self-loop guarantees deg >= 1
}

// exclusive scan over cnt[n] -> offs[n]; chunk of 1024 per block (256 thr x 4 elems)
__global__ void scan1_kernel(const int* __restrict__ cnt, int* __restrict__ offs,
                             int* __restrict__ blockSums, int n) {
  __shared__ int waveTot[4];
  int t = threadIdx.x;
  int lane = t & 63, wv = t >> 6;
  int base = blockIdx.x * 1024 + t * 4;
  int v[4];
  int s = 0;
#pragma unroll
  for (int j = 0; j < 4; j++) {
    v[j] = (base + j < n) ? cnt[base + j] : 0;
    s += v[j];
  }
  int ps = wave_incl_scan(s, lane);
  if (lane == 63) waveTot[wv] = ps;
  __syncthreads();
  int waveOff = 0;
#pragma unroll
  for (int w = 0; w < 4; w++) waveOff += (w < wv) ? waveTot[w] : 0;
  int excl = waveOff + ps - s;
#pragma unroll
  for (int j = 0; j < 4; j++) {
    if (base + j < n) offs[base + j] = excl;
    excl += v[j];
  }
  if (t == TPB - 1) blockSums[blockIdx.x] = waveOff + ps;
}

__global__ void scan2_kernel(int* __restrict__ blockSums, int nb) {
  int lane = threadIdx.x;  // 64 threads
  int carry = 0;
  for (int b = 0; b < nb; b += 64) {
    int i = b + lane;
    int v = (i < nb) ? blockSums[i] : 0;
    int ps = wave_incl_scan(v, lane);
    if (i < nb) blockSums[i] = carry + ps - v;
    carry += __shfl(ps, 63);
  }
}

__global__ void scan3_kernel(int* __restrict__ offs, const int* __restrict__ blockSums, int n) {
  int i = blockIdx.x * TPB + threadIdx.x;
  if (i < n) offs[i] += blockSums[i >> 10];
}

__global__ void scatter_kernel(const int* __restrict__ row, const int* __restrict__ col,
                               const float* __restrict__ dinv, const int* __restrict__ offs,
                               int* __restrict__ cursor, int* __restrict__ csr_row,
                               float* __restrict__ csr_norm, int e) {
  int i = blockIdx.x * TPB + threadIdx.x;
  if (i < e) {
    int r = row[i], c = col[i];
    int p = offs[c] + atomicAdd(&cursor[c], 1);
    csr_row[p] = r;
    csr_norm[p] = dinv[r];  // dinv[col] factored into the aggregation epilogue
  }
}

// out[n,M] = x[n,K] @ W[K,M]; W staged in LDS; one row per wave, lane = out col
template <int K, int M>
__global__ void gemm_kernel(const float* __restrict__ x, const float* __restrict__ W,
                            float* __restrict__ out, int n) {
  __shared__ float Ws[K * M];
  for (int i = threadIdx.x; i < K * M; i += TPB) Ws[i] = W[i];
  __syncthreads();
  int lane = threadIdx.x & 63, wv = threadIdx.x >> 6;
  int c = lane < M ? lane : 0;
  for (int r = blockIdx.x * (TPB / 64) + wv; r < n; r += gridDim.x * (TPB / 64)) {
    const float4* xr4 = (const float4*)(x + (size_t)r * K);
    float acc = 0.f;
#pragma unroll 4
    for (int k4 = 0; k4 < K / 4; k4++) {
      float4 xv = xr4[k4];
      acc += xv.x * Ws[(k4 * 4 + 0) * M + c];
      acc += xv.y * Ws[(k4 * 4 + 1) * M + c];
      acc += xv.z * Ws[(k4 * 4 + 2) * M + c];
      acc += xv.w * Ws[(k4 * 4 + 3) * M + c];
    }
    if (lane < M) out[(size_t)r * M + lane] = acc;
  }
}

// one wave per node: lane f accumulates feature f over incoming CSR edges
template <int M, bool RELU>
__global__ void agg_kernel(const float* __restrict__ xw, const float* __restrict__ dinv,
                           const int* __restrict__ csr_row, const float* __restrict__ csr_norm,
                           const int* __restrict__ offs, const float* __restrict__ bias,
                           float* __restrict__ out, int n, int etot) {
  int lane = threadIdx.x & 63, wv = threadIdx.x >> 6;
  int c = lane < M ? lane : 0;
  int i = blockIdx.x * (TPB / 64) + wv;
  if (i >= n) return;
  int beg = offs[i];
  int end = (i + 1 < n) ? offs[i + 1] : etot;
  float di = dinv[i];
  float acc = xw[(size_t)i * M + c] * di;  // self-loop (outer di applied below)
  for (int e = beg; e < end; e++) {
    int r = csr_row[e];
    float nrm = csr_norm[e];
    acc += xw[(size_t)r * M + c] * nrm;
  }
  acc = acc * di + bias[c];
  if (RELU) acc = fmaxf(acc, 0.f);
  if (lane < M) out[(size_t)i * M + c] = acc;
}

extern "C" void kernel_launch(void* const* d_in, const int* in_sizes, int n_in,
                              void* d_out, int out_size, void* d_ws, size_t ws_size,
                              hipStream_t stream) {
  const float* x  = (const float*)d_in[0];
  const int*   ei = (const int*)d_in[1];
  const float* W1 = (const float*)d_in[2];
  const float* b1 = (const float*)d_in[3];
  const float* W2 = (const float*)d_in[4];
  const float* b2 = (const float*)d_in[5];
  const float* W3 = (const float*)d_in[6];
  const float* b3 = (const float*)d_in[7];

  int n = in_sizes[0] / 128;
  int e = in_sizes[1] / 2;
  const int* rowA = ei;      // edge_index[0] = source
  const int* colA = ei + e;  // edge_index[1] = destination (segment id)

  size_t off = 0;
  auto alloc = [&](size_t bytes) {
    void* p = (char*)d_ws + off;
    off += (bytes + 255) & ~(size_t)255;
    return p;
  };
  float* bufA      = (float*)alloc((size_t)n * 64 * 4);
  float* bufB      = (float*)alloc((size_t)n * 64 * 4);
  int*   cnt       = (int*)alloc((size_t)n * 4);
  int*   cursor    = (int*)alloc((size_t)n * 4);
  int*   offs      = (int*)alloc((size_t)n * 4);
  float* dinv      = (float*)alloc((size_t)n * 4);
  int*   csr_row   = (int*)alloc((size_t)e * 4);
  float* csr_norm  = (float*)alloc((size_t)e * 4);
  int*   blockSums = (int*)alloc(1024 * 4);
  (void)ws_size; (void)n_in; (void)out_size;

  hipMemsetAsync(cnt, 0, (size_t)n * 4, stream);
  hipMemsetAsync(cursor, 0, (size_t)n * 4, stream);

  int ge = (e + TPB - 1) / TPB;
  int gn = (n + TPB - 1) / TPB;
  int nb = (n + 1023) / 1024;
  count_kernel<<<ge, TPB, 0, stream>>>(colA, cnt, e);
  dinv_kernel<<<gn, TPB, 0, stream>>>(cnt, dinv, n);
  scan1_kernel<<<nb, TPB, 0, stream>>>(cnt, offs, blockSums, n);
  scan2_kernel<<<1, 64, 0, stream>>>(blockSums, nb);
  scan3_kernel<<<gn, TPB, 0, stream>>>(offs, blockSums, n);
  scatter_kernel<<<ge, TPB, 0, stream>>>(rowA, colA, dinv, offs, cursor, csr_row, csr_norm, e);

  int gagg = (n + 3) / 4;  // one wave per node, 4 waves/block
  gemm_kernel<128, 64><<<1024, TPB, 0, stream>>>(x, W1, bufA, n);
  agg_kernel<64, true><<<gagg, TPB, 0, stream>>>(bufA, dinv, csr_row, csr_norm, offs, b1, bufB, n, e);
  gemm_kernel<64, 64><<<1024, TPB, 0, stream>>>(bufB, W2, bufA, n);
  agg_kernel<64, true><<<gagg, TPB, 0, stream>>>(bufA, dinv, csr_row, csr_norm, offs, b2, bufB, n, e);
  gemm_kernel<64, 40><<<1024, TPB, 0, stream>>>(bufB, W3, bufA, n);
  agg_kernel<40, false><<<gagg, TPB, 0, stream>>>(bufA, dinv, csr_row, csr_norm, offs, b3, (float*)d_out, n, e);
}

// Round 2
// 751.484 us; speedup vs baseline: 1.2301x; 1.2301x over previous
//
#include <hip/hip_runtime.h>

constexpr int TPB = 256;

__device__ __forceinline__ int wave_incl_scan(int x, int lane) {
#pragma unroll
  for (int d = 1; d < 64; d <<= 1) {
    int y = __shfl_up(x, d);
    if (lane >= d) x += y;
  }
  return x;
}

// ---------------- CSR build (grouped by destination) ----------------

__global__ void count_kernel(const int* __restrict__ col, int* __restrict__ cnt, int e) {
  int i = blockIdx.x * TPB + threadIdx.x;
  if (i < e) atomicAdd(&cnt[col[i]], 1);
}

__global__ void dinv_kernel(const int* __restrict__ cnt, float* __restrict__ dinv, int n) {
  int i = blockIdx.x * TPB + threadIdx.x;
  if (i < n) dinv[i] = rsqrtf(1.0f + (float)cnt[i]);  // self-loop guarantees deg >= 1
}

__global__ void scan1_kernel(const int* __restrict__ cnt, int* __restrict__ offs,
                             int* __restrict__ blockSums, int n) {
  __shared__ int waveTot[4];
  int t = threadIdx.x;
  int lane = t & 63, wv = t >> 6;
  int base = blockIdx.x * 1024 + t * 4;
  int v[4];
  int s = 0;
#pragma unroll
  for (int j = 0; j < 4; j++) {
    v[j] = (base + j < n) ? cnt[base + j] : 0;
    s += v[j];
  }
  int ps = wave_incl_scan(s, lane);
  if (lane == 63) waveTot[wv] = ps;
  __syncthreads();
  int waveOff = 0;
#pragma unroll
  for (int w = 0; w < 4; w++) waveOff += (w < wv) ? waveTot[w] : 0;
  int excl = waveOff + ps - s;
#pragma unroll
  for (int j = 0; j < 4; j++) {
    if (base + j < n) offs[base + j] = excl;
    excl += v[j];
  }
  if (t == TPB - 1) blockSums[blockIdx.x] = waveOff + ps;
}

__global__ void scan2_kernel(int* __restrict__ blockSums, int nb) {
  int lane = threadIdx.x;  // 64 threads
  int carry = 0;
  for (int b = 0; b < nb; b += 64) {
    int i = b + lane;
    int v = (i < nb) ? blockSums[i] : 0;
    int ps = wave_incl_scan(v, lane);
    if (i < nb) blockSums[i] = carry + ps - v;
    carry += __shfl(ps, 63);
  }
}

__global__ void scan3_kernel(int* __restrict__ offs, const int* __restrict__ blockSums, int n) {
  int i = blockIdx.x * TPB + threadIdx.x;
  if (i < n) offs[i] += blockSums[i >> 10];
}

__global__ void scatter_kernel(const int* __restrict__ row, const int* __restrict__ col,
                               const float* __restrict__ dinv, const int* __restrict__ offs,
                               int* __restrict__ cursor, int* __restrict__ csr_row,
                               float* __restrict__ csr_norm, int e) {
  int i = blockIdx.x * TPB + threadIdx.x;
  if (i < e) {
    int r = row[i], c = col[i];
    int p = offs[c] + atomicAdd(&cursor[c], 1);
    csr_row[p] = r;
    csr_norm[p] = dinv[r];  // dinv[col] factored into the aggregation epilogue
  }
}

// ---------------- GEMM: lane = row, W^T through the scalar pipe ----------------

__global__ void transpose_kernel(const float* __restrict__ W, float* __restrict__ WT,
                                 int K, int M) {
  int idx = blockIdx.x * TPB + threadIdx.x;
  if (idx < K * M) {
    int k = idx / M, c = idx % M;
    WT[(size_t)c * K + k] = W[idx];
  }
}

// out[n,M] = x[n,K] @ W[K,M].  One lane per row; acc[M] in VGPRs; W values are
// wave-uniform (WT row-major, scalar loads) so each FMA is v_fmac with SGPR src.
template <int K, int M>
__global__ __launch_bounds__(64) void gemm_rt_kernel(const float* __restrict__ x,
                                                     const float* __restrict__ WT,
                                                     float* __restrict__ out, int n) {
  constexpr int CH = 32;  // k-chunk per iteration (one 128B line per lane for K=128)
  int lane = threadIdx.x;
  int r = blockIdx.x * 64 + lane;
  int rc = r < n ? r : n - 1;  // clamp keeps OOB lanes' loads in-bounds
  const float4* xr = (const float4*)(x + (size_t)rc * K);
  float acc[M];
#pragma unroll
  for (int c = 0; c < M; c++) acc[c] = 0.f;
#pragma unroll 1
  for (int k0 = 0; k0 < K; k0 += CH) {
    float4 xc[CH / 4];
#pragma unroll
    for (int j = 0; j < CH / 4; j++) xc[j] = xr[k0 / 4 + j];
    const float* xs = (const float*)xc;
#pragma unroll
    for (int c = 0; c < M; c++) {
      const float* wt = WT + (size_t)c * K + k0;  // wave-uniform -> s_load
      float a = acc[c];
#pragma unroll
      for (int j = 0; j < CH; j++) a = fmaf(wt[j], xs[j], a);
      acc[c] = a;
    }
  }
  if (r < n) {
    float4* o4 = (float4*)(out + (size_t)r * M);
#pragma unroll
    for (int c = 0; c < M; c += 4) {
      float4 v = {acc[c], acc[c + 1], acc[c + 2], acc[c + 3]};
      o4[c / 4] = v;
    }
  }
}

// ---------------- Aggregation: multi-stream gathers per wave ----------------

// M=64: 4 edge-slots x 16 lanes x float4. 4 concurrent gather chains per wave.
template <bool RELU>
__global__ __launch_bounds__(256) void agg64_kernel(
    const float4* __restrict__ xw4, const float* __restrict__ dinv,
    const int* __restrict__ csr_row, const float* __restrict__ csr_norm,
    const int* __restrict__ offs, const float* __restrict__ bias,
    float4* __restrict__ out4, int n, int etot) {
  int lane = threadIdx.x & 63, wv = threadIdx.x >> 6;
  int slot = lane >> 4, fl = lane & 15;
  int i = blockIdx.x * (TPB / 64) + wv;
  if (i >= n) return;
  int beg = offs[i];
  int end = (i + 1 < n) ? offs[i + 1] : etot;
  float di = dinv[i];
  float4 acc = {0.f, 0.f, 0.f, 0.f};
  if (slot == 0) {  // self-loop term (outer di applied in epilogue)
    float4 s = xw4[(size_t)i * 16 + fl];
    acc.x = s.x * di; acc.y = s.y * di; acc.z = s.z * di; acc.w = s.w * di;
  }
  for (int e = beg + slot; e < end; e += 4) {
    int r = csr_row[e];
    float nrm = csr_norm[e];
    float4 v = xw4[(size_t)r * 16 + fl];
    acc.x = fmaf(v.x, nrm, acc.x);
    acc.y = fmaf(v.y, nrm, acc.y);
    acc.z = fmaf(v.z, nrm, acc.z);
    acc.w = fmaf(v.w, nrm, acc.w);
  }
#pragma unroll
  for (int d = 16; d <= 32; d <<= 1) {
    acc.x += __shfl_xor(acc.x, d);
    acc.y += __shfl_xor(acc.y, d);
    acc.z += __shfl_xor(acc.z, d);
    acc.w += __shfl_xor(acc.w, d);
  }
  if (lane < 16) {
    const float4* b4 = (const float4*)bias;
    float4 b = b4[fl];
    float4 o;
    o.x = acc.x * di + b.x;
    o.y = acc.y * di + b.y;
    o.z = acc.z * di + b.z;
    o.w = acc.w * di + b.w;
    if (RELU) {
      o.x = fmaxf(o.x, 0.f); o.y = fmaxf(o.y, 0.f);
      o.z = fmaxf(o.z, 0.f); o.w = fmaxf(o.w, 0.f);
    }
    out4[(size_t)i * 16 + fl] = o;
  }
}

// M=40: 6 edge-slots x 10 lanes x float4 (lanes 60..63 idle).
__global__ __launch_bounds__(256) void agg40_kernel(
    const float4* __restrict__ xw4, const float* __restrict__ dinv,
    const int* __restrict__ csr_row, const float* __restrict__ csr_norm,
    const int* __restrict__ offs, const float* __restrict__ bias,
    float4* __restrict__ out4, int n, int etot) {
  int lane = threadIdx.x & 63, wv = threadIdx.x >> 6;
  int slot = lane / 10, fl = lane % 10;
  int i = blockIdx.x * (TPB / 64) + wv;
  if (i >= n) return;
  int beg = offs[i];
  int end = (i + 1 < n) ? offs[i + 1] : etot;
  float di = dinv[i];
  if (slot >= 6) { beg = 0; end = 0; fl = 0; }  // idle lanes: no edges
  float4 acc = {0.f, 0.f, 0.f, 0.f};
  if (slot == 0) {
    float4 s = xw4[(size_t)i * 10 + fl];
    acc.x = s.x * di; acc.y = s.y * di; acc.z = s.z * di; acc.w = s.w * di;
  }
  for (int e = beg + slot; e < end; e += 6) {
    int r = csr_row[e];
    float nrm = csr_norm[e];
    float4 v = xw4[(size_t)r * 10 + fl];
    acc.x = fmaf(v.x, nrm, acc.x);
    acc.y = fmaf(v.y, nrm, acc.y);
    acc.z = fmaf(v.z, nrm, acc.z);
    acc.w = fmaf(v.w, nrm, acc.w);
  }
  // slots {0,1,2} += slots {3,4,5}
  {
    float ax = __shfl(acc.x, lane + 30), ay = __shfl(acc.y, lane + 30);
    float az = __shfl(acc.z, lane + 30), aw = __shfl(acc.w, lane + 30);
    acc.x += ax; acc.y += ay; acc.z += az; acc.w += aw;
  }
  // lanes 0..9 += lanes +10, +20 (reads are pre-update within each statement pair)
  {
    float ax1 = __shfl(acc.x, lane + 10), ax2 = __shfl(acc.x, lane + 20);
    float ay1 = __shfl(acc.y, lane + 10), ay2 = __shfl(acc.y, lane + 20);
    float az1 = __shfl(acc.z, lane + 10), az2 = __shfl(acc.z, lane + 20);
    float aw1 = __shfl(acc.w, lane + 10), aw2 = __shfl(acc.w, lane + 20);
    acc.x += ax1 + ax2; acc.y += ay1 + ay2;
    acc.z += az1 + az2; acc.w += aw1 + aw2;
  }
  if (lane < 10) {
    const float4* b4 = (const float4*)bias;
    float4 b = b4[fl];
    float4 o;
    o.x = acc.x * di + b.x;
    o.y = acc.y * di + b.y;
    o.z = acc.z * di + b.z;
    o.w = acc.w * di + b.w;
    out4[(size_t)i * 10 + fl] = o;
  }
}

// ---------------- launcher ----------------

extern "C" void kernel_launch(void* const* d_in, const int* in_sizes, int n_in,
                              void* d_out, int out_size, void* d_ws, size_t ws_size,
                              hipStream_t stream) {
  const float* x  = (const float*)d_in[0];
  const int*   ei = (const int*)d_in[1];
  const float* W1 = (const float*)d_in[2];
  const float* b1 = (const float*)d_in[3];
  const float* W2 = (const float*)d_in[4];
  const float* b2 = (const float*)d_in[5];
  const float* W3 = (const float*)d_in[6];
  const float* b3 = (const float*)d_in[7];

  int n = in_sizes[0] / 128;
  int e = in_sizes[1] / 2;
  const int* rowA = ei;      // edge_index[0] = source
  const int* colA = ei + e;  // edge_index[1] = destination (segment id)

  size_t off = 0;
  auto alloc = [&](size_t bytes) {
    void* p = (char*)d_ws + off;
    off += (bytes + 255) & ~(size_t)255;
    return p;
  };
  float* bufA      = (float*)alloc((size_t)n * 64 * 4);
  float* bufB      = (float*)alloc((size_t)n * 64 * 4);
  int*   cnt       = (int*)alloc((size_t)n * 4);
  int*   cursor    = (int*)alloc((size_t)n * 4);
  int*   offs      = (int*)alloc((size_t)n * 4);
  float* dinv      = (float*)alloc((size_t)n * 4);
  int*   csr_row   = (int*)alloc((size_t)e * 4);
  float* csr_norm  = (float*)alloc((size_t)e * 4);
  int*   blockSums = (int*)alloc(1024 * 4);
  float* WT1       = (float*)alloc((size_t)128 * 64 * 4);
  float* WT2       = (float*)alloc((size_t)64 * 64 * 4);
  float* WT3       = (float*)alloc((size_t)64 * 40 * 4);
  (void)ws_size; (void)n_in; (void)out_size;

  hipMemsetAsync(cnt, 0, (size_t)n * 4, stream);
  hipMemsetAsync(cursor, 0, (size_t)n * 4, stream);

  int ge = (e + TPB - 1) / TPB;
  int gn = (n + TPB - 1) / TPB;
  int nb = (n + 1023) / 1024;
  count_kernel<<<ge, TPB, 0, stream>>>(colA, cnt, e);
  dinv_kernel<<<gn, TPB, 0, stream>>>(cnt, dinv, n);
  scan1_kernel<<<nb, TPB, 0, stream>>>(cnt, offs, blockSums, n);
  scan2_kernel<<<1, 64, 0, stream>>>(blockSums, nb);
  scan3_kernel<<<gn, TPB, 0, stream>>>(offs, blockSums, n);
  scatter_kernel<<<ge, TPB, 0, stream>>>(rowA, colA, dinv, offs, cursor, csr_row, csr_norm, e);

  transpose_kernel<<<(128 * 64 + TPB - 1) / TPB, TPB, 0, stream>>>(W1, WT1, 128, 64);
  transpose_kernel<<<(64 * 64 + TPB - 1) / TPB, TPB, 0, stream>>>(W2, WT2, 64, 64);
  transpose_kernel<<<(64 * 40 + TPB - 1) / TPB, TPB, 0, stream>>>(W3, WT3, 64, 40);

  int grow = (n + 63) / 64;
  int gagg = (n + 3) / 4;  // one wave per node, 4 waves/block
  gemm_rt_kernel<128, 64><<<grow, 64, 0, stream>>>(x, WT1, bufA, n);
  agg64_kernel<true><<<gagg, TPB, 0, stream>>>((const float4*)bufA, dinv, csr_row, csr_norm,
                                               offs, b1, (float4*)bufB, n, e);
  gemm_rt_kernel<64, 64><<<grow, 64, 0, stream>>>(bufB, WT2, bufA, n);
  agg64_kernel<true><<<gagg, TPB, 0, stream>>>((const float4*)bufA, dinv, csr_row, csr_norm,
                                               offs, b2, (float4*)bufB, n, e);
  gemm_rt_kernel<64, 40><<<grow, 64, 0, stream>>>(bufB, WT3, bufA, n);
  agg40_kernel<<<gagg, TPB, 0, stream>>>((const float4*)bufA, dinv, csr_row, csr_norm,
                                         offs, b3, (float4*)d_out, n, e);
}

// Round 3
// 723.822 us; speedup vs baseline: 1.2771x; 1.0382x over previous
//
#include <hip/hip_runtime.h>

constexpr int TPB = 256;

__device__ __forceinline__ int wave_incl_scan(int x, int lane) {
#pragma unroll
  for (int d = 1; d < 64; d <<= 1) {
    int y = __shfl_up(x, d);
    if (lane >= d) x += y;
  }
  return x;
}

// ---------------- CSR build (grouped by destination) ----------------

__global__ void count_kernel(const int* __restrict__ col, int* __restrict__ cnt, int e) {
  int i = blockIdx.x * TPB + threadIdx.x;
  if (i < e) atomicAdd(&cnt[col[i]], 1);
}

__global__ void dinv_kernel(const int* __restrict__ cnt, float* __restrict__ dinv, int n) {
  int i = blockIdx.x * TPB + threadIdx.x;
  if (i < n) dinv[i] = rsqrtf(1.0f + (float)cnt[i]);  // self-loop guarantees deg >= 1
}

__global__ void scan1_kernel(const int* __restrict__ cnt, int* __restrict__ offs,
                             int* __restrict__ blockSums, int n) {
  __shared__ int waveTot[4];
  int t = threadIdx.x;
  int lane = t & 63, wv = t >> 6;
  int base = blockIdx.x * 1024 + t * 4;
  int v[4];
  int s = 0;
#pragma unroll
  for (int j = 0; j < 4; j++) {
    v[j] = (base + j < n) ? cnt[base + j] : 0;
    s += v[j];
  }
  int ps = wave_incl_scan(s, lane);
  if (lane == 63) waveTot[wv] = ps;
  __syncthreads();
  int waveOff = 0;
#pragma unroll
  for (int w = 0; w < 4; w++) waveOff += (w < wv) ? waveTot[w] : 0;
  int excl = waveOff + ps - s;
#pragma unroll
  for (int j = 0; j < 4; j++) {
    if (base + j < n) offs[base + j] = excl;
    excl += v[j];
  }
  if (t == TPB - 1) blockSums[blockIdx.x] = waveOff + ps;
}

__global__ void scan2_kernel(int* __restrict__ blockSums, int nb) {
  int lane = threadIdx.x;  // 64 threads
  int carry = 0;
  for (int b = 0; b < nb; b += 64) {
    int i = b + lane;
    int v = (i < nb) ? blockSums[i] : 0;
    int ps = wave_incl_scan(v, lane);
    if (i < nb) blockSums[i] = carry + ps - v;
    carry += __shfl(ps, 63);
  }
}

__global__ void scan3_kernel(int* __restrict__ offs, const int* __restrict__ blockSums, int n) {
  int i = blockIdx.x * TPB + threadIdx.x;
  if (i < n) offs[i] += blockSums[i >> 10];
}

__global__ void scatter_kernel(const int* __restrict__ row, const int* __restrict__ col,
                               const float* __restrict__ dinv, const int* __restrict__ offs,
                               int* __restrict__ cursor, int* __restrict__ csr_row,
                               float* __restrict__ csr_norm, int e) {
  int i = blockIdx.x * TPB + threadIdx.x;
  if (i < e) {
    int r = row[i], c = col[i];
    int p = offs[c] + atomicAdd(&cursor[c], 1);
    csr_row[p] = r;
    csr_norm[p] = dinv[r];  // dinv[col] factored into the aggregation epilogue
  }
}

// ---------------- GEMM ----------------

__global__ void transpose_kernel(const float* __restrict__ W, float* __restrict__ WT,
                                 int K, int M) {
  int idx = blockIdx.x * TPB + threadIdx.x;
  if (idx < K * M) {
    int k = idx / M, c = idx % M;
    WT[(size_t)c * K + k] = W[idx];
  }
}

// out[n,M] = x[n,K] @ W[K,M].  Lane = row; x staged through LDS (coalesced
// global loads, transposed [k][row] layout, +1 pad -> conflict-free b32 reads);
// W wave-uniform via WT + readfirstlane -> s_load + v_fmac with SGPR operand.
// Block = 256 thr covers RB=128 rows; wave w: rows (w&1)*64.., cols (w>>1)*MSUB..
template <int K, int M, int MSUB>
__global__ __launch_bounds__(256) void gemm_lds_kernel(const float* __restrict__ x,
                                                       const float* __restrict__ WT,
                                                       float* __restrict__ out, int n) {
  constexpr int KC = 32;       // k-chunk
  constexpr int RB = 128;      // rows per block
  constexpr int RP = RB + 1;   // padded row-stride (transposed layout)
  __shared__ float xs[KC * RP];
  int t = threadIdx.x;
  int lane = t & 63;
  int wvu = __builtin_amdgcn_readfirstlane(t >> 6);
  int rowl = (wvu & 1) * 64 + lane;  // local row in [0,RB)
  int c0 = (wvu >> 1) * MSUB;
  int row0 = blockIdx.x * RB;
  int r = row0 + rowl;

  float acc[MSUB];
#pragma unroll
  for (int c = 0; c < MSUB; c++) acc[c] = 0.f;

#pragma unroll 1
  for (int k0 = 0; k0 < K; k0 += KC) {
    __syncthreads();  // previous chunk's reads done before overwrite
#pragma unroll
    for (int j = 0; j < (RB * KC) / (TPB * 4); j++) {
      int li = t + TPB * j;
      int row = li / (KC / 4);
      int k4 = li % (KC / 4);
      int rg = row0 + row;
      if (rg >= n) rg = n - 1;
      float4 v = *(const float4*)(x + (size_t)rg * K + k0 + k4 * 4);
      xs[(k4 * 4 + 0) * RP + row] = v.x;
      xs[(k4 * 4 + 1) * RP + row] = v.y;
      xs[(k4 * 4 + 2) * RP + row] = v.z;
      xs[(k4 * 4 + 3) * RP + row] = v.w;
    }
    __syncthreads();
    float xv[KC];
#pragma unroll
    for (int kk = 0; kk < KC; kk++) xv[kk] = xs[kk * RP + rowl];
    const float* wtb = WT + (size_t)c0 * K + k0;
#pragma unroll
    for (int c = 0; c < MSUB; c++) {
      const float* wt = wtb + (size_t)c * K;  // wave-uniform -> scalar loads
      float a = acc[c];
#pragma unroll
      for (int kk = 0; kk < KC; kk++) a = fmaf(wt[kk], xv[kk], a);
      acc[c] = a;
    }
  }
  if (r < n) {
    float4* o4 = (float4*)(out + (size_t)r * M + c0);
#pragma unroll
    for (int c = 0; c < MSUB; c += 4) {
      float4 v = {acc[c], acc[c + 1], acc[c + 2], acc[c + 3]};
      o4[c / 4] = v;
    }
  }
}

// ---------------- Aggregation: multi-stream gathers per wave ----------------

// M=64: 4 edge-slots x 16 lanes x float4. 4 concurrent gather chains per wave.
template <bool RELU>
__global__ __launch_bounds__(256) void agg64_kernel(
    const float4* __restrict__ xw4, const float* __restrict__ dinv,
    const int* __restrict__ csr_row, const float* __restrict__ csr_norm,
    const int* __restrict__ offs, const float* __restrict__ bias,
    float4* __restrict__ out4, int n, int etot) {
  int lane = threadIdx.x & 63, wv = threadIdx.x >> 6;
  int slot = lane >> 4, fl = lane & 15;
  int i = blockIdx.x * (TPB / 64) + wv;
  if (i >= n) return;
  int beg = offs[i];
  int end = (i + 1 < n) ? offs[i + 1] : etot;
  float di = dinv[i];
  float4 acc = {0.f, 0.f, 0.f, 0.f};
  if (slot == 0) {  // self-loop term (outer di applied in epilogue)
    float4 s = xw4[(size_t)i * 16 + fl];
    acc.x = s.x * di; acc.y = s.y * di; acc.z = s.z * di; acc.w = s.w * di;
  }
  for (int e = beg + slot; e < end; e += 4) {
    int r = csr_row[e];
    float nrm = csr_norm[e];
    float4 v = xw4[(size_t)r * 16 + fl];
    acc.x = fmaf(v.x, nrm, acc.x);
    acc.y = fmaf(v.y, nrm, acc.y);
    acc.z = fmaf(v.z, nrm, acc.z);
    acc.w = fmaf(v.w, nrm, acc.w);
  }
#pragma unroll
  for (int d = 16; d <= 32; d <<= 1) {
    acc.x += __shfl_xor(acc.x, d);
    acc.y += __shfl_xor(acc.y, d);
    acc.z += __shfl_xor(acc.z, d);
    acc.w += __shfl_xor(acc.w, d);
  }
  if (lane < 16) {
    const float4* b4 = (const float4*)bias;
    float4 b = b4[fl];
    float4 o;
    o.x = acc.x * di + b.x;
    o.y = acc.y * di + b.y;
    o.z = acc.z * di + b.z;
    o.w = acc.w * di + b.w;
    if (RELU) {
      o.x = fmaxf(o.x, 0.f); o.y = fmaxf(o.y, 0.f);
      o.z = fmaxf(o.z, 0.f); o.w = fmaxf(o.w, 0.f);
    }
    out4[(size_t)i * 16 + fl] = o;
  }
}

// M=40: 6 edge-slots x 10 lanes x float4 (lanes 60..63 idle).
__global__ __launch_bounds__(256) void agg40_kernel(
    const float4* __restrict__ xw4, const float* __restrict__ dinv,
    const int* __restrict__ csr_row, const float* __restrict__ csr_norm,
    const int* __restrict__ offs, const float* __restrict__ bias,
    float4* __restrict__ out4, int n, int etot) {
  int lane = threadIdx.x & 63, wv = threadIdx.x >> 6;
  int slot = lane / 10, fl = lane % 10;
  int i = blockIdx.x * (TPB / 64) + wv;
  if (i >= n) return;
  int beg = offs[i];
  int end = (i + 1 < n) ? offs[i + 1] : etot;
  float di = dinv[i];
  if (slot >= 6) { beg = 0; end = 0; fl = 0; }  // idle lanes: no edges
  float4 acc = {0.f, 0.f, 0.f, 0.f};
  if (slot == 0) {
    float4 s = xw4[(size_t)i * 10 + fl];
    acc.x = s.x * di; acc.y = s.y * di; acc.z = s.z * di; acc.w = s.w * di;
  }
  for (int e = beg + slot; e < end; e += 6) {
    int r = csr_row[e];
    float nrm = csr_norm[e];
    float4 v = xw4[(size_t)r * 10 + fl];
    acc.x = fmaf(v.x, nrm, acc.x);
    acc.y = fmaf(v.y, nrm, acc.y);
    acc.z = fmaf(v.z, nrm, acc.z);
    acc.w = fmaf(v.w, nrm, acc.w);
  }
  // slots {0,1,2} += slots {3,4,5}
  {
    float ax = __shfl(acc.x, lane + 30), ay = __shfl(acc.y, lane + 30);
    float az = __shfl(acc.z, lane + 30), aw = __shfl(acc.w, lane + 30);
    acc.x += ax; acc.y += ay; acc.z += az; acc.w += aw;
  }
  // lanes 0..9 += lanes +10, +20
  {
    float ax1 = __shfl(acc.x, lane + 10), ax2 = __shfl(acc.x, lane + 20);
    float ay1 = __shfl(acc.y, lane + 10), ay2 = __shfl(acc.y, lane + 20);
    float az1 = __shfl(acc.z, lane + 10), az2 = __shfl(acc.z, lane + 20);
    float aw1 = __shfl(acc.w, lane + 10), aw2 = __shfl(acc.w, lane + 20);
    acc.x += ax1 + ax2; acc.y += ay1 + ay2;
    acc.z += az1 + az2; acc.w += aw1 + aw2;
  }
  if (lane < 10) {
    const float4* b4 = (const float4*)bias;
    float4 b = b4[fl];
    float4 o;
    o.x = acc.x * di + b.x;
    o.y = acc.y * di + b.y;
    o.z = acc.z * di + b.z;
    o.w = acc.w * di + b.w;
    out4[(size_t)i * 10 + fl] = o;
  }
}

// ---------------- launcher ----------------

extern "C" void kernel_launch(void* const* d_in, const int* in_sizes, int n_in,
                              void* d_out, int out_size, void* d_ws, size_t ws_size,
                              hipStream_t stream) {
  const float* x  = (const float*)d_in[0];
  const int*   ei = (const int*)d_in[1];
  const float* W1 = (const float*)d_in[2];
  const float* b1 = (const float*)d_in[3];
  const float* W2 = (const float*)d_in[4];
  const float* b2 = (const float*)d_in[5];
  const float* W3 = (const float*)d_in[6];
  const float* b3 = (const float*)d_in[7];

  int n = in_sizes[0] / 128;
  int e = in_sizes[1] / 2;
  const int* rowA = ei;      // edge_index[0] = source
  const int* colA = ei + e;  // edge_index[1] = destination (segment id)

  size_t off = 0;
  auto alloc = [&](size_t bytes) {
    void* p = (char*)d_ws + off;
    off += (bytes + 255) & ~(size_t)255;
    return p;
  };
  float* bufA      = (float*)alloc((size_t)n * 64 * 4);
  float* bufB      = (float*)alloc((size_t)n * 64 * 4);
  int*   cnt       = (int*)alloc((size_t)n * 4);
  int*   cursor    = (int*)alloc((size_t)n * 4);
  int*   offs      = (int*)alloc((size_t)n * 4);
  float* dinv      = (float*)alloc((size_t)n * 4);
  int*   csr_row   = (int*)alloc((size_t)e * 4);
  float* csr_norm  = (float*)alloc((size_t)e * 4);
  int*   blockSums = (int*)alloc(1024 * 4);
  float* WT1       = (float*)alloc((size_t)128 * 64 * 4);
  float* WT2       = (float*)alloc((size_t)64 * 64 * 4);
  float* WT3       = (float*)alloc((size_t)64 * 40 * 4);
  (void)ws_size; (void)n_in; (void)out_size;

  hipMemsetAsync(cnt, 0, (size_t)n * 4, stream);
  hipMemsetAsync(cursor, 0, (size_t)n * 4, stream);

  int ge = (e + TPB - 1) / TPB;
  int gn = (n + TPB - 1) / TPB;
  int nb = (n + 1023) / 1024;
  count_kernel<<<ge, TPB, 0, stream>>>(colA, cnt, e);
  dinv_kernel<<<gn, TPB, 0, stream>>>(cnt, dinv, n);
  scan1_kernel<<<nb, TPB, 0, stream>>>(cnt, offs, blockSums, n);
  scan2_kernel<<<1, 64, 0, stream>>>(blockSums, nb);
  scan3_kernel<<<gn, TPB, 0, stream>>>(offs, blockSums, n);
  scatter_kernel<<<ge, TPB, 0, stream>>>(rowA, colA, dinv, offs, cursor, csr_row, csr_norm, e);

  transpose_kernel<<<(128 * 64 + TPB - 1) / TPB, TPB, 0, stream>>>(W1, WT1, 128, 64);
  transpose_kernel<<<(64 * 64 + TPB - 1) / TPB, TPB, 0, stream>>>(W2, WT2, 64, 64);
  transpose_kernel<<<(64 * 40 + TPB - 1) / TPB, TPB, 0, stream>>>(W3, WT3, 64, 40);

  int ggemm = (n + 127) / 128;
  int gagg = (n + 3) / 4;  // one wave per node, 4 waves/block
  gemm_lds_kernel<128, 64, 32><<<ggemm, TPB, 0, stream>>>(x, WT1, bufA, n);
  agg64_kernel<true><<<gagg, TPB, 0, stream>>>((const float4*)bufA, dinv, csr_row, csr_norm,
                                               offs, b1, (float4*)bufB, n, e);
  gemm_lds_kernel<64, 64, 32><<<ggemm, TPB, 0, stream>>>(bufB, WT2, bufA, n);
  agg64_kernel<true><<<gagg, TPB, 0, stream>>>((const float4*)bufA, dinv, csr_row, csr_norm,
                                               offs, b2, (float4*)bufB, n, e);
  gemm_lds_kernel<64, 40, 20><<<ggemm, TPB, 0, stream>>>(bufB, WT3, bufA, n);
  agg40_kernel<<<gagg, TPB, 0, stream>>>((const float4*)bufA, dinv, csr_row, csr_norm,
                                         offs, b3, (float4*)d_out, n, e);
}

// Round 4
// 527.817 us; speedup vs baseline: 1.7514x; 1.3713x over previous
//
#include <hip/hip_runtime.h>

constexpr int TPB = 256;

__device__ __forceinline__ int wave_incl_scan(int x, int lane) {
#pragma unroll
  for (int d = 1; d < 64; d <<= 1) {
    int y = __shfl_up(x, d);
    if (lane >= d) x += y;
  }
  return x;
}

// ---------------- CSR build (grouped by destination) ----------------

__global__ void count_kernel(const int* __restrict__ col, int* __restrict__ cnt, int e) {
  int i = blockIdx.x * TPB + threadIdx.x;
  if (i < e) atomicAdd(&cnt[col[i]], 1);
}

__global__ void dinv_kernel(const int* __restrict__ cnt, float* __restrict__ dinv, int n) {
  int i = blockIdx.x * TPB + threadIdx.x;
  if (i < n) dinv[i] = rsqrtf(1.0f + (float)cnt[i]);  // self-loop guarantees deg >= 1
}

__global__ void scan1_kernel(const int* __restrict__ cnt, int* __restrict__ offs,
                             int* __restrict__ blockSums, int n) {
  __shared__ int waveTot[4];
  int t = threadIdx.x;
  int lane = t & 63, wv = t >> 6;
  int base = blockIdx.x * 1024 + t * 4;
  int v[4];
  int s = 0;
#pragma unroll
  for (int j = 0; j < 4; j++) {
    v[j] = (base + j < n) ? cnt[base + j] : 0;
    s += v[j];
  }
  int ps = wave_incl_scan(s, lane);
  if (lane == 63) waveTot[wv] = ps;
  __syncthreads();
  int waveOff = 0;
#pragma unroll
  for (int w = 0; w < 4; w++) waveOff += (w < wv) ? waveTot[w] : 0;
  int excl = waveOff + ps - s;
#pragma unroll
  for (int j = 0; j < 4; j++) {
    if (base + j < n) offs[base + j] = excl;
    excl += v[j];
  }
  if (t == TPB - 1) blockSums[blockIdx.x] = waveOff + ps;
}

__global__ void scan2_kernel(int* __restrict__ blockSums, int nb) {
  int lane = threadIdx.x;  // 64 threads
  int carry = 0;
  for (int b = 0; b < nb; b += 64) {
    int i = b + lane;
    int v = (i < nb) ? blockSums[i] : 0;
    int ps = wave_incl_scan(v, lane);
    if (i < nb) blockSums[i] = carry + ps - v;
    carry += __shfl(ps, 63);
  }
}

__global__ void scan3_kernel(int* __restrict__ offs, const int* __restrict__ blockSums, int n) {
  int i = blockIdx.x * TPB + threadIdx.x;
  if (i < n) offs[i] += blockSums[i >> 10];
}

__global__ void scatter_kernel(const int* __restrict__ row, const int* __restrict__ col,
                               const float* __restrict__ dinv, const int* __restrict__ offs,
                               int* __restrict__ cursor, int* __restrict__ csr_row,
                               float* __restrict__ csr_norm, int e) {
  int i = blockIdx.x * TPB + threadIdx.x;
  if (i < e) {
    int r = row[i], c = col[i];
    int p = offs[c] + atomicAdd(&cursor[c], 1);
    csr_row[p] = r;
    csr_norm[p] = dinv[r];  // dinv[col] factored into the aggregation epilogue
  }
}

// ---------------- GEMM: register-tiled, both operands from LDS ----------------

// out[n,M] = x[n,K] @ W[K,M].  Block: RB=128 rows x all M cols, 256 threads.
// Thread (rg = t&31, cg = t>>5): TM=4 rows x TN cols (32*TN*8 == 128*M).
// x staged per KC-chunk transposed xs[k][row] (coalesced global, b128 LDS reads);
// W staged whole into Ws[K*M] once (broadcast/2-way reads, free).
template <int K, int M, int TN>
__global__ __launch_bounds__(256) void gemm_tile_kernel(const float* __restrict__ x,
                                                        const float* __restrict__ W,
                                                        float* __restrict__ out, int n) {
  constexpr int KC = 32;       // k-chunk for x staging
  constexpr int RB = 128;      // rows per block
  constexpr int RP = RB + 1;   // padded row stride
  constexpr int TM = 4;        // rows per thread
  __shared__ float xs[KC * RP];
  __shared__ float Ws[K * M];
  int t = threadIdx.x;
  int rg = t & 31, cg = t >> 5;
  int row0 = blockIdx.x * RB;
  int r0 = row0 + rg * TM;
  int c0 = cg * TN;

  // stage all of W (K*M <= 8192 floats)
#pragma unroll
  for (int i = t * 4; i < K * M; i += TPB * 4) {
    *(float4*)&Ws[i] = *(const float4*)&W[i];
  }

  float acc[TM][TN];
#pragma unroll
  for (int i = 0; i < TM; i++)
#pragma unroll
    for (int j = 0; j < TN; j++) acc[i][j] = 0.f;

#pragma unroll 1
  for (int k0 = 0; k0 < K; k0 += KC) {
    __syncthreads();  // previous chunk's reads (and W stage at iter 0) done
#pragma unroll
    for (int j = 0; j < (RB * KC) / (TPB * 4); j++) {
      int li = t + TPB * j;
      int row = li / (KC / 4);
      int k4 = li % (KC / 4);
      int rgl = row0 + row;
      if (rgl >= n) rgl = n - 1;
      float4 v = *(const float4*)(x + (size_t)rgl * K + k0 + k4 * 4);
      xs[(k4 * 4 + 0) * RP + row] = v.x;
      xs[(k4 * 4 + 1) * RP + row] = v.y;
      xs[(k4 * 4 + 2) * RP + row] = v.z;
      xs[(k4 * 4 + 3) * RP + row] = v.w;
    }
    __syncthreads();
#pragma unroll
    for (int kk = 0; kk < KC; kk++) {
      float4 a = *(const float4*)&xs[kk * RP + rg * TM];
      float b[TN];
#pragma unroll
      for (int j = 0; j < TN; j++) b[j] = Ws[(k0 + kk) * M + c0 + j];
      float av[TM] = {a.x, a.y, a.z, a.w};
#pragma unroll
      for (int i = 0; i < TM; i++)
#pragma unroll
        for (int j = 0; j < TN; j++) acc[i][j] = fmaf(av[i], b[j], acc[i][j]);
    }
  }

#pragma unroll
  for (int i = 0; i < TM; i++) {
    int r = r0 + i;
    if (r < n) {
      float* o = out + (size_t)r * M + c0;
#pragma unroll
      for (int j = 0; j < TN; j++) o[j] = acc[i][j];
    }
  }
}

// ---------------- Aggregation: multi-stream gathers per wave ----------------

// M=64: 4 edge-slots x 16 lanes x float4. 4 concurrent gather chains per wave.
template <bool RELU>
__global__ __launch_bounds__(256) void agg64_kernel(
    const float4* __restrict__ xw4, const float* __restrict__ dinv,
    const int* __restrict__ csr_row, const float* __restrict__ csr_norm,
    const int* __restrict__ offs, const float* __restrict__ bias,
    float4* __restrict__ out4, int n, int etot) {
  int lane = threadIdx.x & 63, wv = threadIdx.x >> 6;
  int slot = lane >> 4, fl = lane & 15;
  int i = blockIdx.x * (TPB / 64) + wv;
  if (i >= n) return;
  int beg = offs[i];
  int end = (i + 1 < n) ? offs[i + 1] : etot;
  float di = dinv[i];
  float4 acc = {0.f, 0.f, 0.f, 0.f};
  if (slot == 0) {  // self-loop term (outer di applied in epilogue)
    float4 s = xw4[(size_t)i * 16 + fl];
    acc.x = s.x * di; acc.y = s.y * di; acc.z = s.z * di; acc.w = s.w * di;
  }
  for (int e = beg + slot; e < end; e += 4) {
    int r = csr_row[e];
    float nrm = csr_norm[e];
    float4 v = xw4[(size_t)r * 16 + fl];
    acc.x = fmaf(v.x, nrm, acc.x);
    acc.y = fmaf(v.y, nrm, acc.y);
    acc.z = fmaf(v.z, nrm, acc.z);
    acc.w = fmaf(v.w, nrm, acc.w);
  }
#pragma unroll
  for (int d = 16; d <= 32; d <<= 1) {
    acc.x += __shfl_xor(acc.x, d);
    acc.y += __shfl_xor(acc.y, d);
    acc.z += __shfl_xor(acc.z, d);
    acc.w += __shfl_xor(acc.w, d);
  }
  if (lane < 16) {
    const float4* b4 = (const float4*)bias;
    float4 b = b4[fl];
    float4 o;
    o.x = acc.x * di + b.x;
    o.y = acc.y * di + b.y;
    o.z = acc.z * di + b.z;
    o.w = acc.w * di + b.w;
    if (RELU) {
      o.x = fmaxf(o.x, 0.f); o.y = fmaxf(o.y, 0.f);
      o.z = fmaxf(o.z, 0.f); o.w = fmaxf(o.w, 0.f);
    }
    out4[(size_t)i * 16 + fl] = o;
  }
}

// M=40: 6 edge-slots x 10 lanes x float4 (lanes 60..63 idle).
__global__ __launch_bounds__(256) void agg40_kernel(
    const float4* __restrict__ xw4, const float* __restrict__ dinv,
    const int* __restrict__ csr_row, const float* __restrict__ csr_norm,
    const int* __restrict__ offs, const float* __restrict__ bias,
    float4* __restrict__ out4, int n, int etot) {
  int lane = threadIdx.x & 63, wv = threadIdx.x >> 6;
  int slot = lane / 10, fl = lane % 10;
  int i = blockIdx.x * (TPB / 64) + wv;
  if (i >= n) return;
  int beg = offs[i];
  int end = (i + 1 < n) ? offs[i + 1] : etot;
  float di = dinv[i];
  if (slot >= 6) { beg = 0; end = 0; fl = 0; }  // idle lanes: no edges
  float4 acc = {0.f, 0.f, 0.f, 0.f};
  if (slot == 0) {
    float4 s = xw4[(size_t)i * 10 + fl];
    acc.x = s.x * di; acc.y = s.y * di; acc.z = s.z * di; acc.w = s.w * di;
  }
  for (int e = beg + slot; e < end; e += 6) {
    int r = csr_row[e];
    float nrm = csr_norm[e];
    float4 v = xw4[(size_t)r * 10 + fl];
    acc.x = fmaf(v.x, nrm, acc.x);
    acc.y = fmaf(v.y, nrm, acc.y);
    acc.z = fmaf(v.z, nrm, acc.z);
    acc.w = fmaf(v.w, nrm, acc.w);
  }
  // slots {0,1,2} += slots {3,4,5}
  {
    float ax = __shfl(acc.x, lane + 30), ay = __shfl(acc.y, lane + 30);
    float az = __shfl(acc.z, lane + 30), aw = __shfl(acc.w, lane + 30);
    acc.x += ax; acc.y += ay; acc.z += az; acc.w += aw;
  }
  // lanes 0..9 += lanes +10, +20
  {
    float ax1 = __shfl(acc.x, lane + 10), ax2 = __shfl(acc.x, lane + 20);
    float ay1 = __shfl(acc.y, lane + 10), ay2 = __shfl(acc.y, lane + 20);
    float az1 = __shfl(acc.z, lane + 10), az2 = __shfl(acc.z, lane + 20);
    float aw1 = __shfl(acc.w, lane + 10), aw2 = __shfl(acc.w, lane + 20);
    acc.x += ax1 + ax2; acc.y += ay1 + ay2;
    acc.z += az1 + az2; acc.w += aw1 + aw2;
  }
  if (lane < 10) {
    const float4* b4 = (const float4*)bias;
    float4 b = b4[fl];
    float4 o;
    o.x = acc.x * di + b.x;
    o.y = acc.y * di + b.y;
    o.z = acc.z * di + b.z;
    o.w = acc.w * di + b.w;
    out4[(size_t)i * 10 + fl] = o;
  }
}

// ---------------- launcher ----------------

extern "C" void kernel_launch(void* const* d_in, const int* in_sizes, int n_in,
                              void* d_out, int out_size, void* d_ws, size_t ws_size,
                              hipStream_t stream) {
  const float* x  = (const float*)d_in[0];
  const int*   ei = (const int*)d_in[1];
  const float* W1 = (const float*)d_in[2];
  const float* b1 = (const float*)d_in[3];
  const float* W2 = (const float*)d_in[4];
  const float* b2 = (const float*)d_in[5];
  const float* W3 = (const float*)d_in[6];
  const float* b3 = (const float*)d_in[7];

  int n = in_sizes[0] / 128;
  int e = in_sizes[1] / 2;
  const int* rowA = ei;      // edge_index[0] = source
  const int* colA = ei + e;  // edge_index[1] = destination (segment id)

  size_t off = 0;
  auto alloc = [&](size_t bytes) {
    void* p = (char*)d_ws + off;
    off += (bytes + 255) & ~(size_t)255;
    return p;
  };
  float* bufA      = (float*)alloc((size_t)n * 64 * 4);
  float* bufB      = (float*)alloc((size_t)n * 64 * 4);
  int*   cnt       = (int*)alloc((size_t)n * 4);
  int*   cursor    = (int*)alloc((size_t)n * 4);
  int*   offs      = (int*)alloc((size_t)n * 4);
  float* dinv      = (float*)alloc((size_t)n * 4);
  int*   csr_row   = (int*)alloc((size_t)e * 4);
  float* csr_norm  = (float*)alloc((size_t)e * 4);
  int*   blockSums = (int*)alloc(1024 * 4);
  (void)ws_size; (void)n_in; (void)out_size;

  hipMemsetAsync(cnt, 0, (size_t)n * 4, stream);
  hipMemsetAsync(cursor, 0, (size_t)n * 4, stream);

  int ge = (e + TPB - 1) / TPB;
  int gn = (n + TPB - 1) / TPB;
  int nb = (n + 1023) / 1024;
  count_kernel<<<ge, TPB, 0, stream>>>(colA, cnt, e);
  dinv_kernel<<<gn, TPB, 0, stream>>>(cnt, dinv, n);
  scan1_kernel<<<nb, TPB, 0, stream>>>(cnt, offs, blockSums, n);
  scan2_kernel<<<1, 64, 0, stream>>>(blockSums, nb);
  scan3_kernel<<<gn, TPB, 0, stream>>>(offs, blockSums, n);
  scatter_kernel<<<ge, TPB, 0, stream>>>(rowA, colA, dinv, offs, cursor, csr_row, csr_norm, e);

  int ggemm = (n + 127) / 128;
  int gagg = (n + 3) / 4;  // one wave per node, 4 waves/block
  gemm_tile_kernel<128, 64, 8><<<ggemm, TPB, 0, stream>>>(x, W1, bufA, n);
  agg64_kernel<true><<<gagg, TPB, 0, stream>>>((const float4*)bufA, dinv, csr_row, csr_norm,
                                               offs, b1, (float4*)bufB, n, e);
  gemm_tile_kernel<64, 64, 8><<<ggemm, TPB, 0, stream>>>(bufB, W2, bufA, n);
  agg64_kernel<true><<<gagg, TPB, 0, stream>>>((const float4*)bufA, dinv, csr_row, csr_norm,
                                               offs, b2, (float4*)bufB, n, e);
  gemm_tile_kernel<64, 40, 5><<<ggemm, TPB, 0, stream>>>(bufB, W3, bufA, n);
  agg40_kernel<<<gagg, TPB, 0, stream>>>((const float4*)bufA, dinv, csr_row, csr_norm,
                                         offs, b3, (float4*)d_out, n, e);
}

// Round 5
// 437.783 us; speedup vs baseline: 2.1116x; 1.2057x over previous
//
#include <hip/hip_runtime.h>

constexpr int TPB = 256;
constexpr int SH = 9;          // bucket = 512 consecutive destinations
constexpr int BD = 1 << SH;    // 512 dests per bucket (max 512 buckets -> n <= 262144)
constexpr int CHUNK = 4096;    // edges per binning block

__device__ __forceinline__ int wave_incl_scan(int x, int lane) {
#pragma unroll
  for (int d = 1; d < 64; d <<= 1) {
    int y = __shfl_up(x, d);
    if (lane >= d) x += y;
  }
  return x;
}

// ---------------- binned CSR build (grouped by destination) ----------------

// coarse histogram of col>>SH
__global__ void hist_kernel(const int* __restrict__ col, int* __restrict__ bcnt,
                            int e, int nb) {
  __shared__ int h[512];
  for (int i = threadIdx.x; i < nb; i += TPB) h[i] = 0;
  __syncthreads();
  int base = blockIdx.x * CHUNK;
  int lim = min(base + CHUNK, e);
  for (int i = base + threadIdx.x; i < lim; i += TPB)
    atomicAdd(&h[col[i] >> SH], 1);
  __syncthreads();
  for (int i = threadIdx.x; i < nb; i += TPB)
    if (h[i]) atomicAdd(&bcnt[i], h[i]);
}

// exclusive scan of bucket counts -> bbase[nb+1]; bcur initialized to bbase
__global__ void bscan_kernel(const int* __restrict__ bcnt, int* __restrict__ bbase,
                             int* __restrict__ bcur, int nb) {
  int lane = threadIdx.x;  // 64 threads
  int carry = 0;
  for (int b = 0; b < nb; b += 64) {
    int i = b + lane;
    int v = (i < nb) ? bcnt[i] : 0;
    int ps = wave_incl_scan(v, lane);
    int ex = carry + ps - v;
    if (i < nb) { bbase[i] = ex; bcur[i] = ex; }
    carry += __shfl(ps, 63);
  }
  if (lane == 0) bbase[nb] = carry;
}

// partition edges into buckets: {row, col} appended per bucket.
// Per-block LDS histogram -> one global reservation per (block,bucket) ->
// sequential runs per bucket => tiny active write frontier (no amplification).
__global__ void bin_kernel(const int* __restrict__ row, const int* __restrict__ col,
                           int* __restrict__ bcur, int2* __restrict__ binned,
                           int e, int nb) {
  __shared__ int h[512];
  __shared__ int base[512];
  for (int i = threadIdx.x; i < nb; i += TPB) h[i] = 0;
  __syncthreads();
  int cb = blockIdx.x * CHUNK;
  int lim = min(cb + CHUNK, e);
  for (int i = cb + threadIdx.x; i < lim; i += TPB)
    atomicAdd(&h[col[i] >> SH], 1);
  __syncthreads();
  for (int i = threadIdx.x; i < nb; i += TPB) {
    int c = h[i];
    base[i] = c ? atomicAdd(&bcur[i], c) : 0;
    h[i] = 0;  // reuse as local cursor
  }
  __syncthreads();
  for (int i = cb + threadIdx.x; i < lim; i += TPB) {
    int c = col[i];  // L2-hot re-read of this block's own chunk
    int b = c >> SH;
    int p = base[b] + atomicAdd(&h[b], 1);
    binned[p] = make_int2(row[i], c);
  }
}

// per bucket: fine per-dest counts in LDS -> LDS scan -> offs + dinv
__global__ __launch_bounds__(512) void fine_count_kernel(
    const int2* __restrict__ binned, const int* __restrict__ bbase,
    int* __restrict__ offs, float* __restrict__ dinv, int n) {
  __shared__ int cnt[BD];
  __shared__ int wsum[8];
  int t = threadIdx.x, lane = t & 63, wv = t >> 6;
  int b = blockIdx.x;
  int c0 = b << SH;
  int ndst = min(BD, n - c0);
  cnt[t] = 0;
  __syncthreads();
  int beg = bbase[b], end = bbase[b + 1];
  for (int i = beg + t; i < end; i += 512)
    atomicAdd(&cnt[binned[i].y - c0], 1);
  __syncthreads();
  int v = cnt[t];
  int ps = wave_incl_scan(v, lane);
  if (lane == 63) wsum[wv] = ps;
  __syncthreads();
  int woff = 0;
#pragma unroll
  for (int w = 0; w < 8; w++) woff += (w < wv) ? wsum[w] : 0;
  int ex = woff + ps - v;
  if (t < ndst) {
    offs[c0 + t] = beg + ex;
    dinv[c0 + t] = rsqrtf(1.0f + (float)v);  // deg = incoming + self-loop
  }
}

// per bucket: place fused {r, dinv[r]} records into the bucket's contiguous range
__global__ __launch_bounds__(512) void place_kernel(
    const int2* __restrict__ binned, const int* __restrict__ bbase,
    const int* __restrict__ offs, const float* __restrict__ dinv,
    int2* __restrict__ csr, int n) {
  __shared__ int cur[BD];
  int t = threadIdx.x;
  int b = blockIdx.x;
  int c0 = b << SH;
  int ndst = min(BD, n - c0);
  cur[t] = (t < ndst) ? offs[c0 + t] : 0;
  __syncthreads();
  int beg = bbase[b], end = bbase[b + 1];
  for (int i = beg + t; i < end; i += 512) {
    int2 rc = binned[i];
    int p = atomicAdd(&cur[rc.y - c0], 1);
    csr[p] = make_int2(rc.x, __float_as_int(dinv[rc.x]));
  }
}

// ---------------- GEMM: register-tiled, both operands from LDS ----------------

template <int K, int M, int TN>
__global__ __launch_bounds__(256) void gemm_tile_kernel(const float* __restrict__ x,
                                                        const float* __restrict__ W,
                                                        float* __restrict__ out, int n) {
  constexpr int KC = 32;
  constexpr int RB = 128;
  constexpr int RP = RB + 1;
  constexpr int TM = 4;
  __shared__ float xs[KC * RP];
  __shared__ float Ws[K * M];
  int t = threadIdx.x;
  int rg = t & 31, cg = t >> 5;
  int row0 = blockIdx.x * RB;
  int r0 = row0 + rg * TM;
  int c0 = cg * TN;

#pragma unroll
  for (int i = t * 4; i < K * M; i += TPB * 4) {
    *(float4*)&Ws[i] = *(const float4*)&W[i];
  }

  float acc[TM][TN];
#pragma unroll
  for (int i = 0; i < TM; i++)
#pragma unroll
    for (int j = 0; j < TN; j++) acc[i][j] = 0.f;

#pragma unroll 1
  for (int k0 = 0; k0 < K; k0 += KC) {
    __syncthreads();
#pragma unroll
    for (int j = 0; j < (RB * KC) / (TPB * 4); j++) {
      int li = t + TPB * j;
      int row = li / (KC / 4);
      int k4 = li % (KC / 4);
      int rgl = row0 + row;
      if (rgl >= n) rgl = n - 1;
      float4 v = *(const float4*)(x + (size_t)rgl * K + k0 + k4 * 4);
      xs[(k4 * 4 + 0) * RP + row] = v.x;
      xs[(k4 * 4 + 1) * RP + row] = v.y;
      xs[(k4 * 4 + 2) * RP + row] = v.z;
      xs[(k4 * 4 + 3) * RP + row] = v.w;
    }
    __syncthreads();
#pragma unroll
    for (int kk = 0; kk < KC; kk++) {
      float4 a = *(const float4*)&xs[kk * RP + rg * TM];
      float bb[TN];
#pragma unroll
      for (int j = 0; j < TN; j++) bb[j] = Ws[(k0 + kk) * M + c0 + j];
      float av[TM] = {a.x, a.y, a.z, a.w};
#pragma unroll
      for (int i = 0; i < TM; i++)
#pragma unroll
        for (int j = 0; j < TN; j++) acc[i][j] = fmaf(av[i], bb[j], acc[i][j]);
    }
  }

#pragma unroll
  for (int i = 0; i < TM; i++) {
    int r = r0 + i;
    if (r < n) {
      float* o = out + (size_t)r * M + c0;
#pragma unroll
      for (int j = 0; j < TN; j++) o[j] = acc[i][j];
    }
  }
}

// ---------------- Aggregation: multi-stream gathers per wave ----------------

// M=64: 4 edge-slots x 16 lanes x float4; fused 8B edge records.
template <bool RELU>
__global__ __launch_bounds__(256) void agg64_kernel(
    const float4* __restrict__ xw4, const float* __restrict__ dinv,
    const int2* __restrict__ csr, const int* __restrict__ offs,
    const float* __restrict__ bias, float4* __restrict__ out4, int n, int etot) {
  int lane = threadIdx.x & 63, wv = threadIdx.x >> 6;
  int slot = lane >> 4, fl = lane & 15;
  int i = blockIdx.x * (TPB / 64) + wv;
  if (i >= n) return;
  int beg = offs[i];
  int end = (i + 1 < n) ? offs[i + 1] : etot;
  float di = dinv[i];
  float4 acc = {0.f, 0.f, 0.f, 0.f};
  if (slot == 0) {  // self-loop (outer di applied in epilogue)
    float4 s = xw4[(size_t)i * 16 + fl];
    acc.x = s.x * di; acc.y = s.y * di; acc.z = s.z * di; acc.w = s.w * di;
  }
  for (int e = beg + slot; e < end; e += 4) {
    int2 er = csr[e];
    float nrm = __int_as_float(er.y);
    float4 v = xw4[(size_t)er.x * 16 + fl];
    acc.x = fmaf(v.x, nrm, acc.x);
    acc.y = fmaf(v.y, nrm, acc.y);
    acc.z = fmaf(v.z, nrm, acc.z);
    acc.w = fmaf(v.w, nrm, acc.w);
  }
#pragma unroll
  for (int d = 16; d <= 32; d <<= 1) {
    acc.x += __shfl_xor(acc.x, d);
    acc.y += __shfl_xor(acc.y, d);
    acc.z += __shfl_xor(acc.z, d);
    acc.w += __shfl_xor(acc.w, d);
  }
  if (lane < 16) {
    const float4* b4 = (const float4*)bias;
    float4 b = b4[fl];
    float4 o;
    o.x = acc.x * di + b.x;
    o.y = acc.y * di + b.y;
    o.z = acc.z * di + b.z;
    o.w = acc.w * di + b.w;
    if (RELU) {
      o.x = fmaxf(o.x, 0.f); o.y = fmaxf(o.y, 0.f);
      o.z = fmaxf(o.z, 0.f); o.w = fmaxf(o.w, 0.f);
    }
    out4[(size_t)i * 16 + fl] = o;
  }
}

// M=40: 6 edge-slots x 10 lanes x float4 (lanes 60..63 idle).
__global__ __launch_bounds__(256) void agg40_kernel(
    const float4* __restrict__ xw4, const float* __restrict__ dinv,
    const int2* __restrict__ csr, const int* __restrict__ offs,
    const float* __restrict__ bias, float4* __restrict__ out4, int n, int etot) {
  int lane = threadIdx.x & 63, wv = threadIdx.x >> 6;
  int slot = lane / 10, fl = lane % 10;
  int i = blockIdx.x * (TPB / 64) + wv;
  if (i >= n) return;
  int beg = offs[i];
  int end = (i + 1 < n) ? offs[i + 1] : etot;
  float di = dinv[i];
  if (slot >= 6) { beg = 0; end = 0; fl = 0; }
  float4 acc = {0.f, 0.f, 0.f, 0.f};
  if (slot == 0) {
    float4 s = xw4[(size_t)i * 10 + fl];
    acc.x = s.x * di; acc.y = s.y * di; acc.z = s.z * di; acc.w = s.w * di;
  }
  for (int e = beg + slot; e < end; e += 6) {
    int2 er = csr[e];
    float nrm = __int_as_float(er.y);
    float4 v = xw4[(size_t)er.x * 10 + fl];
    acc.x = fmaf(v.x, nrm, acc.x);
    acc.y = fmaf(v.y, nrm, acc.y);
    acc.z = fmaf(v.z, nrm, acc.z);
    acc.w = fmaf(v.w, nrm, acc.w);
  }
  {
    float ax = __shfl(acc.x, lane + 30), ay = __shfl(acc.y, lane + 30);
    float az = __shfl(acc.z, lane + 30), aw = __shfl(acc.w, lane + 30);
    acc.x += ax; acc.y += ay; acc.z += az; acc.w += aw;
  }
  {
    float ax1 = __shfl(acc.x, lane + 10), ax2 = __shfl(acc.x, lane + 20);
    float ay1 = __shfl(acc.y, lane + 10), ay2 = __shfl(acc.y, lane + 20);
    float az1 = __shfl(acc.z, lane + 10), az2 = __shfl(acc.z, lane + 20);
    float aw1 = __shfl(acc.w, lane + 10), aw2 = __shfl(acc.w, lane + 20);
    acc.x += ax1 + ax2; acc.y += ay1 + ay2;
    acc.z += az1 + az2; acc.w += aw1 + aw2;
  }
  if (lane < 10) {
    const float4* b4 = (const float4*)bias;
    float4 b = b4[fl];
    float4 o;
    o.x = acc.x * di + b.x;
    o.y = acc.y * di + b.y;
    o.z = acc.z * di + b.z;
    o.w = acc.w * di + b.w;
    out4[(size_t)i * 10 + fl] = o;
  }
}

// ---------------- launcher ----------------

extern "C" void kernel_launch(void* const* d_in, const int* in_sizes, int n_in,
                              void* d_out, int out_size, void* d_ws, size_t ws_size,
                              hipStream_t stream) {
  const float* x  = (const float*)d_in[0];
  const int*   ei = (const int*)d_in[1];
  const float* W1 = (const float*)d_in[2];
  const float* b1 = (const float*)d_in[3];
  const float* W2 = (const float*)d_in[4];
  const float* b2 = (const float*)d_in[5];
  const float* W3 = (const float*)d_in[6];
  const float* b3 = (const float*)d_in[7];

  int n = in_sizes[0] / 128;
  int e = in_sizes[1] / 2;
  const int* rowA = ei;      // edge_index[0] = source
  const int* colA = ei + e;  // edge_index[1] = destination (segment id)

  size_t off = 0;
  auto alloc = [&](size_t bytes) {
    void* p = (char*)d_ws + off;
    off += (bytes + 255) & ~(size_t)255;
    return p;
  };
  float* bufA  = (float*)alloc((size_t)n * 64 * 4);
  float* bufB  = (float*)alloc((size_t)n * 64 * 4);
  int*   offs  = (int*)alloc((size_t)n * 4);
  float* dinv  = (float*)alloc((size_t)n * 4);
  int2*  csr   = (int2*)alloc((size_t)e * 8);
  int*   bcnt  = (int*)alloc(512 * 4);
  int*   bbase = (int*)alloc(513 * 4);
  int*   bcur  = (int*)alloc(512 * 4);
  // binned {row,col} pairs alias bufA: consumed by place_kernel before gemm1 writes bufA
  int2*  binned = (int2*)bufA;
  (void)ws_size; (void)n_in; (void)out_size;

  int nb = (n + BD - 1) >> SH;        // buckets (<= 512)
  int nch = (e + CHUNK - 1) / CHUNK;  // binning blocks

  hipMemsetAsync(bcnt, 0, 512 * 4, stream);
  hist_kernel<<<nch, TPB, 0, stream>>>(colA, bcnt, e, nb);
  bscan_kernel<<<1, 64, 0, stream>>>(bcnt, bbase, bcur, nb);
  bin_kernel<<<nch, TPB, 0, stream>>>(rowA, colA, bcur, binned, e, nb);
  fine_count_kernel<<<nb, 512, 0, stream>>>(binned, bbase, offs, dinv, n);
  place_kernel<<<nb, 512, 0, stream>>>(binned, bbase, offs, dinv, csr, n);

  int ggemm = (n + 127) / 128;
  int gagg = (n + 3) / 4;  // one wave per node, 4 waves/block
  gemm_tile_kernel<128, 64, 8><<<ggemm, TPB, 0, stream>>>(x, W1, bufA, n);
  agg64_kernel<true><<<gagg, TPB, 0, stream>>>((const float4*)bufA, dinv, csr, offs,
                                               b1, (float4*)bufB, n, e);
  gemm_tile_kernel<64, 64, 8><<<ggemm, TPB, 0, stream>>>(bufB, W2, bufA, n);
  agg64_kernel<true><<<gagg, TPB, 0, stream>>>((const float4*)bufA, dinv, csr, offs,
                                               b2, (float4*)bufB, n, e);
  gemm_tile_kernel<64, 40, 5><<<ggemm, TPB, 0, stream>>>(bufB, W3, bufA, n);
  agg40_kernel<<<gagg, TPB, 0, stream>>>((const float4*)bufA, dinv, csr, offs,
                                         b3, (float4*)d_out, n, e);
}

// Round 6
// 428.590 us; speedup vs baseline: 2.1569x; 1.0214x over previous
//
#include <hip/hip_runtime.h>

constexpr int TPB = 256;
constexpr int SH = 9;          // bucket = 512 consecutive destinations
constexpr int BD = 1 << SH;    // 512 dests per bucket (max 512 buckets -> n <= 262144)
constexpr int CHUNK = 4096;    // edges per binning block

__device__ __forceinline__ int wave_incl_scan(int x, int lane) {
#pragma unroll
  for (int d = 1; d < 64; d <<= 1) {
    int y = __shfl_up(x, d);
    if (lane >= d) x += y;
  }
  return x;
}

// ---------------- binned CSR build (grouped by destination) ----------------

__global__ void hist_kernel(const int* __restrict__ col, int* __restrict__ bcnt,
                            int e, int nb) {
  __shared__ int h[512];
  for (int i = threadIdx.x; i < nb; i += TPB) h[i] = 0;
  __syncthreads();
  int base = blockIdx.x * CHUNK;
  int lim = min(base + CHUNK, e);
  for (int i = base + threadIdx.x; i < lim; i += TPB)
    atomicAdd(&h[col[i] >> SH], 1);
  __syncthreads();
  for (int i = threadIdx.x; i < nb; i += TPB)
    if (h[i]) atomicAdd(&bcnt[i], h[i]);
}

__global__ void bscan_kernel(const int* __restrict__ bcnt, int* __restrict__ bbase,
                             int* __restrict__ bcur, int nb) {
  int lane = threadIdx.x;  // 64 threads
  int carry = 0;
  for (int b = 0; b < nb; b += 64) {
    int i = b + lane;
    int v = (i < nb) ? bcnt[i] : 0;
    int ps = wave_incl_scan(v, lane);
    int ex = carry + ps - v;
    if (i < nb) { bbase[i] = ex; bcur[i] = ex; }
    carry += __shfl(ps, 63);
  }
  if (lane == 0) bbase[nb] = carry;
}

__global__ void bin_kernel(const int* __restrict__ row, const int* __restrict__ col,
                           int* __restrict__ bcur, int2* __restrict__ binned,
                           int e, int nb) {
  __shared__ int h[512];
  __shared__ int base[512];
  for (int i = threadIdx.x; i < nb; i += TPB) h[i] = 0;
  __syncthreads();
  int cb = blockIdx.x * CHUNK;
  int lim = min(cb + CHUNK, e);
  for (int i = cb + threadIdx.x; i < lim; i += TPB)
    atomicAdd(&h[col[i] >> SH], 1);
  __syncthreads();
  for (int i = threadIdx.x; i < nb; i += TPB) {
    int c = h[i];
    base[i] = c ? atomicAdd(&bcur[i], c) : 0;
    h[i] = 0;  // reuse as local cursor
  }
  __syncthreads();
  for (int i = cb + threadIdx.x; i < lim; i += TPB) {
    int c = col[i];  // L2-hot re-read of this block's own chunk
    int b = c >> SH;
    int p = base[b] + atomicAdd(&h[b], 1);
    binned[p] = make_int2(row[i], c);
  }
}

__global__ __launch_bounds__(512) void fine_count_kernel(
    const int2* __restrict__ binned, const int* __restrict__ bbase,
    int* __restrict__ offs, float* __restrict__ dinv, int n) {
  __shared__ int cnt[BD];
  __shared__ int wsum[8];
  int t = threadIdx.x, lane = t & 63, wv = t >> 6;
  int b = blockIdx.x;
  int c0 = b << SH;
  int ndst = min(BD, n - c0);
  cnt[t] = 0;
  __syncthreads();
  int beg = bbase[b], end = bbase[b + 1];
  for (int i = beg + t; i < end; i += 512)
    atomicAdd(&cnt[binned[i].y - c0], 1);
  __syncthreads();
  int v = cnt[t];
  int ps = wave_incl_scan(v, lane);
  if (lane == 63) wsum[wv] = ps;
  __syncthreads();
  int woff = 0;
#pragma unroll
  for (int w = 0; w < 8; w++) woff += (w < wv) ? wsum[w] : 0;
  int ex = woff + ps - v;
  if (t < ndst) {
    offs[c0 + t] = beg + ex;
    dinv[c0 + t] = rsqrtf(1.0f + (float)v);  // deg = incoming + self-loop
  }
}

__global__ __launch_bounds__(512) void place_kernel(
    const int2* __restrict__ binned, const int* __restrict__ bbase,
    const int* __restrict__ offs, const float* __restrict__ dinv,
    int2* __restrict__ csr, int n) {
  __shared__ int cur[BD];
  int t = threadIdx.x;
  int b = blockIdx.x;
  int c0 = b << SH;
  int ndst = min(BD, n - c0);
  cur[t] = (t < ndst) ? offs[c0 + t] : 0;
  __syncthreads();
  int beg = bbase[b], end = bbase[b + 1];
  for (int i = beg + t; i < end; i += 512) {
    int2 rc = binned[i];
    int p = atomicAdd(&cur[rc.y - c0], 1);
    csr[p] = make_int2(rc.x, __float_as_int(dinv[rc.x]));
  }
}

// ---------------- GEMM: register-tiled, both operands from LDS ----------------

template <int K, int M, int TN>
__global__ __launch_bounds__(256) void gemm_tile_kernel(const float* __restrict__ x,
                                                        const float* __restrict__ W,
                                                        float* __restrict__ out, int n) {
  constexpr int KC = 32;
  constexpr int RB = 128;
  constexpr int RP = RB + 1;
  constexpr int TM = 4;
  __shared__ float xs[KC * RP];
  __shared__ float Ws[K * M];
  int t = threadIdx.x;
  int rg = t & 31, cg = t >> 5;
  int row0 = blockIdx.x * RB;
  int r0 = row0 + rg * TM;
  int c0 = cg * TN;

#pragma unroll
  for (int i = t * 4; i < K * M; i += TPB * 4) {
    *(float4*)&Ws[i] = *(const float4*)&W[i];
  }

  float acc[TM][TN];
#pragma unroll
  for (int i = 0; i < TM; i++)
#pragma unroll
    for (int j = 0; j < TN; j++) acc[i][j] = 0.f;

#pragma unroll 1
  for (int k0 = 0; k0 < K; k0 += KC) {
    __syncthreads();
#pragma unroll
    for (int j = 0; j < (RB * KC) / (TPB * 4); j++) {
      int li = t + TPB * j;
      int row = li / (KC / 4);
      int k4 = li % (KC / 4);
      int rgl = row0 + row;
      if (rgl >= n) rgl = n - 1;
      float4 v = *(const float4*)(x + (size_t)rgl * K + k0 + k4 * 4);
      xs[(k4 * 4 + 0) * RP + row] = v.x;
      xs[(k4 * 4 + 1) * RP + row] = v.y;
      xs[(k4 * 4 + 2) * RP + row] = v.z;
      xs[(k4 * 4 + 3) * RP + row] = v.w;
    }
    __syncthreads();
#pragma unroll
    for (int kk = 0; kk < KC; kk++) {
      float4 a = *(const float4*)&xs[kk * RP + rg * TM];
      float bb[TN];
#pragma unroll
      for (int j = 0; j < TN; j++) bb[j] = Ws[(k0 + kk) * M + c0 + j];
      float av[TM] = {a.x, a.y, a.z, a.w};
#pragma unroll
      for (int i = 0; i < TM; i++)
#pragma unroll
        for (int j = 0; j < TN; j++) acc[i][j] = fmaf(av[i], bb[j], acc[i][j]);
    }
  }

#pragma unroll
  for (int i = 0; i < TM; i++) {
    int r = r0 + i;
    if (r < n) {
      float* o = out + (size_t)r * M + c0;
#pragma unroll
      for (int j = 0; j < TN; j++) o[j] = acc[i][j];
    }
  }
}

// ---------------- Aggregation: multi-stream gathers, unrolled for MLP ----------------

// M=64: 4 edge-slots x 16 lanes x float4; 4-way unrolled slot loop ->
// up to 16 independent 256B row-gathers in flight per wave.
template <bool RELU>
__global__ __launch_bounds__(256) void agg64_kernel(
    const float4* __restrict__ xw4, const float* __restrict__ dinv,
    const int2* __restrict__ csr, const int* __restrict__ offs,
    const float* __restrict__ bias, float4* __restrict__ out4, int n, int etot) {
  int lane = threadIdx.x & 63, wv = threadIdx.x >> 6;
  int slot = lane >> 4, fl = lane & 15;
  int i = blockIdx.x * (TPB / 64) + wv;
  if (i >= n) return;
  int beg = offs[i];
  int end = (i + 1 < n) ? offs[i + 1] : etot;
  float di = dinv[i];
  float4 acc = {0.f, 0.f, 0.f, 0.f};
  if (slot == 0) {  // self-loop (outer di applied in epilogue)
    float4 s = xw4[(size_t)i * 16 + fl];
    acc.x = s.x * di; acc.y = s.y * di; acc.z = s.z * di; acc.w = s.w * di;
  }
  int e = beg + slot;
  // unroll-4: edge records e..e+12 sit in one 128B line; 4 independent gathers
  for (; e + 12 < end; e += 16) {
    int2 a0 = csr[e];
    int2 a1 = csr[e + 4];
    int2 a2 = csr[e + 8];
    int2 a3 = csr[e + 12];
    float4 v0 = xw4[(size_t)a0.x * 16 + fl];
    float4 v1 = xw4[(size_t)a1.x * 16 + fl];
    float4 v2 = xw4[(size_t)a2.x * 16 + fl];
    float4 v3 = xw4[(size_t)a3.x * 16 + fl];
    float n0 = __int_as_float(a0.y), n1 = __int_as_float(a1.y);
    float n2 = __int_as_float(a2.y), n3 = __int_as_float(a3.y);
    acc.x = fmaf(v0.x, n0, acc.x); acc.y = fmaf(v0.y, n0, acc.y);
    acc.z = fmaf(v0.z, n0, acc.z); acc.w = fmaf(v0.w, n0, acc.w);
    acc.x = fmaf(v1.x, n1, acc.x); acc.y = fmaf(v1.y, n1, acc.y);
    acc.z = fmaf(v1.z, n1, acc.z); acc.w = fmaf(v1.w, n1, acc.w);
    acc.x = fmaf(v2.x, n2, acc.x); acc.y = fmaf(v2.y, n2, acc.y);
    acc.z = fmaf(v2.z, n2, acc.z); acc.w = fmaf(v2.w, n2, acc.w);
    acc.x = fmaf(v3.x, n3, acc.x); acc.y = fmaf(v3.y, n3, acc.y);
    acc.z = fmaf(v3.z, n3, acc.z); acc.w = fmaf(v3.w, n3, acc.w);
  }
  for (; e < end; e += 4) {
    int2 er = csr[e];
    float nrm = __int_as_float(er.y);
    float4 v = xw4[(size_t)er.x * 16 + fl];
    acc.x = fmaf(v.x, nrm, acc.x);
    acc.y = fmaf(v.y, nrm, acc.y);
    acc.z = fmaf(v.z, nrm, acc.z);
    acc.w = fmaf(v.w, nrm, acc.w);
  }
#pragma unroll
  for (int d = 16; d <= 32; d <<= 1) {
    acc.x += __shfl_xor(acc.x, d);
    acc.y += __shfl_xor(acc.y, d);
    acc.z += __shfl_xor(acc.z, d);
    acc.w += __shfl_xor(acc.w, d);
  }
  if (lane < 16) {
    const float4* b4 = (const float4*)bias;
    float4 b = b4[fl];
    float4 o;
    o.x = acc.x * di + b.x;
    o.y = acc.y * di + b.y;
    o.z = acc.z * di + b.z;
    o.w = acc.w * di + b.w;
    if (RELU) {
      o.x = fmaxf(o.x, 0.f); o.y = fmaxf(o.y, 0.f);
      o.z = fmaxf(o.z, 0.f); o.w = fmaxf(o.w, 0.f);
    }
    out4[(size_t)i * 16 + fl] = o;
  }
}

// M=40: 6 edge-slots x 10 lanes x float4; 2-way unrolled (slots own ~2.7 edges).
__global__ __launch_bounds__(256) void agg40_kernel(
    const float4* __restrict__ xw4, const float* __restrict__ dinv,
    const int2* __restrict__ csr, const int* __restrict__ offs,
    const float* __restrict__ bias, float4* __restrict__ out4, int n, int etot) {
  int lane = threadIdx.x & 63, wv = threadIdx.x >> 6;
  int slot = lane / 10, fl = lane % 10;
  int i = blockIdx.x * (TPB / 64) + wv;
  if (i >= n) return;
  int beg = offs[i];
  int end = (i + 1 < n) ? offs[i + 1] : etot;
  float di = dinv[i];
  if (slot >= 6) { beg = 0; end = 0; fl = 0; }
  float4 acc = {0.f, 0.f, 0.f, 0.f};
  if (slot == 0) {
    float4 s = xw4[(size_t)i * 10 + fl];
    acc.x = s.x * di; acc.y = s.y * di; acc.z = s.z * di; acc.w = s.w * di;
  }
  int e = beg + slot;
  for (; e + 6 < end; e += 12) {
    int2 a0 = csr[e];
    int2 a1 = csr[e + 6];
    float4 v0 = xw4[(size_t)a0.x * 10 + fl];
    float4 v1 = xw4[(size_t)a1.x * 10 + fl];
    float n0 = __int_as_float(a0.y), n1 = __int_as_float(a1.y);
    acc.x = fmaf(v0.x, n0, acc.x); acc.y = fmaf(v0.y, n0, acc.y);
    acc.z = fmaf(v0.z, n0, acc.z); acc.w = fmaf(v0.w, n0, acc.w);
    acc.x = fmaf(v1.x, n1, acc.x); acc.y = fmaf(v1.y, n1, acc.y);
    acc.z = fmaf(v1.z, n1, acc.z); acc.w = fmaf(v1.w, n1, acc.w);
  }
  for (; e < end; e += 6) {
    int2 er = csr[e];
    float nrm = __int_as_float(er.y);
    float4 v = xw4[(size_t)er.x * 10 + fl];
    acc.x = fmaf(v.x, nrm, acc.x);
    acc.y = fmaf(v.y, nrm, acc.y);
    acc.z = fmaf(v.z, nrm, acc.z);
    acc.w = fmaf(v.w, nrm, acc.w);
  }
  {
    float ax = __shfl(acc.x, lane + 30), ay = __shfl(acc.y, lane + 30);
    float az = __shfl(acc.z, lane + 30), aw = __shfl(acc.w, lane + 30);
    acc.x += ax; acc.y += ay; acc.z += az; acc.w += aw;
  }
  {
    float ax1 = __shfl(acc.x, lane + 10), ax2 = __shfl(acc.x, lane + 20);
    float ay1 = __shfl(acc.y, lane + 10), ay2 = __shfl(acc.y, lane + 20);
    float az1 = __shfl(acc.z, lane + 10), az2 = __shfl(acc.z, lane + 20);
    float aw1 = __shfl(acc.w, lane + 10), aw2 = __shfl(acc.w, lane + 20);
    acc.x += ax1 + ax2; acc.y += ay1 + ay2;
    acc.z += az1 + az2; acc.w += aw1 + aw2;
  }
  if (lane < 10) {
    const float4* b4 = (const float4*)bias;
    float4 b = b4[fl];
    float4 o;
    o.x = acc.x * di + b.x;
    o.y = acc.y * di + b.y;
    o.z = acc.z * di + b.z;
    o.w = acc.w * di + b.w;
    out4[(size_t)i * 10 + fl] = o;
  }
}

// ---------------- launcher ----------------

extern "C" void kernel_launch(void* const* d_in, const int* in_sizes, int n_in,
                              void* d_out, int out_size, void* d_ws, size_t ws_size,
                              hipStream_t stream) {
  const float* x  = (const float*)d_in[0];
  const int*   ei = (const int*)d_in[1];
  const float* W1 = (const float*)d_in[2];
  const float* b1 = (const float*)d_in[3];
  const float* W2 = (const float*)d_in[4];
  const float* b2 = (const float*)d_in[5];
  const float* W3 = (const float*)d_in[6];
  const float* b3 = (const float*)d_in[7];

  int n = in_sizes[0] / 128;
  int e = in_sizes[1] / 2;
  const int* rowA = ei;      // edge_index[0] = source
  const int* colA = ei + e;  // edge_index[1] = destination (segment id)

  size_t off = 0;
  auto alloc = [&](size_t bytes) {
    void* p = (char*)d_ws + off;
    off += (bytes + 255) & ~(size_t)255;
    return p;
  };
  float* bufA  = (float*)alloc((size_t)n * 64 * 4);
  float* bufB  = (float*)alloc((size_t)n * 64 * 4);
  int*   offs  = (int*)alloc((size_t)n * 4);
  float* dinv  = (float*)alloc((size_t)n * 4);
  int2*  csr   = (int2*)alloc((size_t)e * 8);
  int*   bcnt  = (int*)alloc(512 * 4);
  int*   bbase = (int*)alloc(513 * 4);
  int*   bcur  = (int*)alloc(512 * 4);
  // binned {row,col} pairs alias bufA: consumed by place_kernel before gemm1 writes bufA
  int2*  binned = (int2*)bufA;
  (void)ws_size; (void)n_in; (void)out_size;

  int nb = (n + BD - 1) >> SH;        // buckets (<= 512)
  int nch = (e + CHUNK - 1) / CHUNK;  // binning blocks

  hipMemsetAsync(bcnt, 0, 512 * 4, stream);
  hist_kernel<<<nch, TPB, 0, stream>>>(colA, bcnt, e, nb);
  bscan_kernel<<<1, 64, 0, stream>>>(bcnt, bbase, bcur, nb);
  bin_kernel<<<nch, TPB, 0, stream>>>(rowA, colA, bcur, binned, e, nb);
  fine_count_kernel<<<nb, 512, 0, stream>>>(binned, bbase, offs, dinv, n);
  place_kernel<<<nb, 512, 0, stream>>>(binned, bbase, offs, dinv, csr, n);

  int ggemm = (n + 127) / 128;
  int gagg = (n + 3) / 4;  // one wave per node, 4 waves/block
  gemm_tile_kernel<128, 64, 8><<<ggemm, TPB, 0, stream>>>(x, W1, bufA, n);
  agg64_kernel<true><<<gagg, TPB, 0, stream>>>((const float4*)bufA, dinv, csr, offs,
                                               b1, (float4*)bufB, n, e);
  gemm_tile_kernel<64, 64, 8><<<ggemm, TPB, 0, stream>>>(bufB, W2, bufA, n);
  agg64_kernel<true><<<gagg, TPB, 0, stream>>>((const float4*)bufA, dinv, csr, offs,
                                               b2, (float4*)bufB, n, e);
  gemm_tile_kernel<64, 40, 5><<<ggemm, TPB, 0, stream>>>(bufB, W3, bufA, n);
  agg40_kernel<<<gagg, TPB, 0, stream>>>((const float4*)bufA, dinv, csr, offs,
                                         b3, (float4*)d_out, n, e);
}

// Round 7
// 396.844 us; speedup vs baseline: 2.3294x; 1.0800x over previous
//
#include <hip/hip_runtime.h>
#include <hip/hip_fp16.h>

constexpr int TPB = 256;
constexpr int SH = 9;          // bucket = 512 consecutive destinations
constexpr int BD = 1 << SH;    // 512 dests per bucket (max 512 buckets -> n <= 262144)
constexpr int CHUNK = 4096;    // edges per binning block

__device__ __forceinline__ int wave_incl_scan(int x, int lane) {
#pragma unroll
  for (int d = 1; d < 64; d <<= 1) {
    int y = __shfl_up(x, d);
    if (lane >= d) x += y;
  }
  return x;
}

// ---------------- binned CSR build (grouped by destination) ----------------

__global__ void hist_kernel(const int* __restrict__ col, int* __restrict__ bcnt,
                            int e, int nb) {
  __shared__ int h[512];
  for (int i = threadIdx.x; i < nb; i += TPB) h[i] = 0;
  __syncthreads();
  int base = blockIdx.x * CHUNK;
  int lim = min(base + CHUNK, e);
  for (int i = base + threadIdx.x; i < lim; i += TPB)
    atomicAdd(&h[col[i] >> SH], 1);
  __syncthreads();
  for (int i = threadIdx.x; i < nb; i += TPB)
    if (h[i]) atomicAdd(&bcnt[i], h[i]);
}

__global__ void bscan_kernel(const int* __restrict__ bcnt, int* __restrict__ bbase,
                             int* __restrict__ bcur, int nb) {
  int lane = threadIdx.x;  // 64 threads
  int carry = 0;
  for (int b = 0; b < nb; b += 64) {
    int i = b + lane;
    int v = (i < nb) ? bcnt[i] : 0;
    int ps = wave_incl_scan(v, lane);
    int ex = carry + ps - v;
    if (i < nb) { bbase[i] = ex; bcur[i] = ex; }
    carry += __shfl(ps, 63);
  }
  if (lane == 0) bbase[nb] = carry;
}

__global__ void bin_kernel(const int* __restrict__ row, const int* __restrict__ col,
                           int* __restrict__ bcur, int2* __restrict__ binned,
                           int e, int nb) {
  __shared__ int h[512];
  __shared__ int base[512];
  for (int i = threadIdx.x; i < nb; i += TPB) h[i] = 0;
  __syncthreads();
  int cb = blockIdx.x * CHUNK;
  int lim = min(cb + CHUNK, e);
  for (int i = cb + threadIdx.x; i < lim; i += TPB)
    atomicAdd(&h[col[i] >> SH], 1);
  __syncthreads();
  for (int i = threadIdx.x; i < nb; i += TPB) {
    int c = h[i];
    base[i] = c ? atomicAdd(&bcur[i], c) : 0;
    h[i] = 0;  // reuse as local cursor
  }
  __syncthreads();
  for (int i = cb + threadIdx.x; i < lim; i += TPB) {
    int c = col[i];  // L2-hot re-read of this block's own chunk
    int b = c >> SH;
    int p = base[b] + atomicAdd(&h[b], 1);
    binned[p] = make_int2(row[i], c);
  }
}

__global__ __launch_bounds__(512) void fine_count_kernel(
    const int2* __restrict__ binned, const int* __restrict__ bbase,
    int* __restrict__ offs, float* __restrict__ dinv, int n) {
  __shared__ int cnt[BD];
  __shared__ int wsum[8];
  int t = threadIdx.x, lane = t & 63, wv = t >> 6;
  int b = blockIdx.x;
  int c0 = b << SH;
  int ndst = min(BD, n - c0);
  cnt[t] = 0;
  __syncthreads();
  int beg = bbase[b], end = bbase[b + 1];
  for (int i = beg + t; i < end; i += 512)
    atomicAdd(&cnt[binned[i].y - c0], 1);
  __syncthreads();
  int v = cnt[t];
  int ps = wave_incl_scan(v, lane);
  if (lane == 63) wsum[wv] = ps;
  __syncthreads();
  int woff = 0;
#pragma unroll
  for (int w = 0; w < 8; w++) woff += (w < wv) ? wsum[w] : 0;
  int ex = woff + ps - v;
  if (t < ndst) {
    offs[c0 + t] = beg + ex;
    dinv[c0 + t] = rsqrtf(1.0f + (float)v);  // deg = incoming + self-loop
  }
}

__global__ __launch_bounds__(512) void place_kernel(
    const int2* __restrict__ binned, const int* __restrict__ bbase,
    const int* __restrict__ offs, const float* __restrict__ dinv,
    int2* __restrict__ csr, int n) {
  __shared__ int cur[BD];
  int t = threadIdx.x;
  int b = blockIdx.x;
  int c0 = b << SH;
  int ndst = min(BD, n - c0);
  cur[t] = (t < ndst) ? offs[c0 + t] : 0;
  __syncthreads();
  int beg = bbase[b], end = bbase[b + 1];
  for (int i = beg + t; i < end; i += 512) {
    int2 rc = binned[i];
    int p = atomicAdd(&cur[rc.y - c0], 1);
    csr[p] = make_int2(rc.x, __float_as_int(dinv[rc.x]));
  }
}

// ---------------- GEMM: register-tiled, fp16 output (fp32 accumulate) ----------------

// layer-1: fp32 input x[n,128] -> fp16 out[n,64]
template <int K, int M, int TN>
__global__ __launch_bounds__(256) void gemm_f32in_kernel(const float* __restrict__ x,
                                                         const float* __restrict__ W,
                                                         __half* __restrict__ out, int n) {
  constexpr int KC = 32;
  constexpr int RB = 128;
  constexpr int RP = RB + 1;
  constexpr int TM = 4;
  __shared__ float xs[KC * RP];
  __shared__ float Ws[K * M];
  int t = threadIdx.x;
  int rg = t & 31, cg = t >> 5;
  int row0 = blockIdx.x * RB;
  int r0 = row0 + rg * TM;
  int c0 = cg * TN;

#pragma unroll
  for (int i = t * 4; i < K * M; i += TPB * 4) *(float4*)&Ws[i] = *(const float4*)&W[i];

  float acc[TM][TN];
#pragma unroll
  for (int i = 0; i < TM; i++)
#pragma unroll
    for (int j = 0; j < TN; j++) acc[i][j] = 0.f;

#pragma unroll 1
  for (int k0 = 0; k0 < K; k0 += KC) {
    __syncthreads();
#pragma unroll
    for (int j = 0; j < (RB * KC) / (TPB * 4); j++) {
      int li = t + TPB * j;
      int row = li / (KC / 4);
      int k4 = li % (KC / 4);
      int rgl = row0 + row;
      if (rgl >= n) rgl = n - 1;
      float4 v = *(const float4*)(x + (size_t)rgl * K + k0 + k4 * 4);
      xs[(k4 * 4 + 0) * RP + row] = v.x;
      xs[(k4 * 4 + 1) * RP + row] = v.y;
      xs[(k4 * 4 + 2) * RP + row] = v.z;
      xs[(k4 * 4 + 3) * RP + row] = v.w;
    }
    __syncthreads();
#pragma unroll
    for (int kk = 0; kk < KC; kk++) {
      float4 a = *(const float4*)&xs[kk * RP + rg * TM];
      float bb[TN];
#pragma unroll
      for (int j = 0; j < TN; j++) bb[j] = Ws[(k0 + kk) * M + c0 + j];
      float av[TM] = {a.x, a.y, a.z, a.w};
#pragma unroll
      for (int i = 0; i < TM; i++)
#pragma unroll
        for (int j = 0; j < TN; j++) acc[i][j] = fmaf(av[i], bb[j], acc[i][j]);
    }
  }

#pragma unroll
  for (int i = 0; i < TM; i++) {
    int r = r0 + i;
    if (r < n) {
      __half* o = out + (size_t)r * M + c0;
#pragma unroll
      for (int j = 0; j < TN; j++) o[j] = __float2half(acc[i][j]);
    }
  }
}

// layers 2/3: fp16 input [n,K] -> fp16 out[n,M] (fp32 math)
template <int K, int M, int TN>
__global__ __launch_bounds__(256) void gemm_f16in_kernel(const __half* __restrict__ x,
                                                         const float* __restrict__ W,
                                                         __half* __restrict__ out, int n) {
  constexpr int KC = 32;
  constexpr int RB = 128;
  constexpr int RP = RB + 1;
  constexpr int TM = 4;
  __shared__ float xs[KC * RP];
  __shared__ float Ws[K * M];
  int t = threadIdx.x;
  int rg = t & 31, cg = t >> 5;
  int row0 = blockIdx.x * RB;
  int r0 = row0 + rg * TM;
  int c0 = cg * TN;

#pragma unroll
  for (int i = t * 4; i < K * M; i += TPB * 4) *(float4*)&Ws[i] = *(const float4*)&W[i];

  float acc[TM][TN];
#pragma unroll
  for (int i = 0; i < TM; i++)
#pragma unroll
    for (int j = 0; j < TN; j++) acc[i][j] = 0.f;

#pragma unroll 1
  for (int k0 = 0; k0 < K; k0 += KC) {
    __syncthreads();
    // stage KC halves per row: each thread loads 8 halves (16B)
#pragma unroll
    for (int j = 0; j < (RB * KC) / (TPB * 8); j++) {
      int li = t + TPB * j;
      int row = li / (KC / 8);
      int k8 = li % (KC / 8);
      int rgl = row0 + row;
      if (rgl >= n) rgl = n - 1;
      union { uint4 u; __half2 h[4]; } cv;
      cv.u = *(const uint4*)(x + (size_t)rgl * K + k0 + k8 * 8);
#pragma unroll
      for (int p = 0; p < 4; p++) {
        float2 f = __half22float2(cv.h[p]);
        xs[(k8 * 8 + p * 2 + 0) * RP + row] = f.x;
        xs[(k8 * 8 + p * 2 + 1) * RP + row] = f.y;
      }
    }
    __syncthreads();
#pragma unroll
    for (int kk = 0; kk < KC; kk++) {
      float4 a = *(const float4*)&xs[kk * RP + rg * TM];
      float bb[TN];
#pragma unroll
      for (int j = 0; j < TN; j++) bb[j] = Ws[(k0 + kk) * M + c0 + j];
      float av[TM] = {a.x, a.y, a.z, a.w};
#pragma unroll
      for (int i = 0; i < TM; i++)
#pragma unroll
        for (int j = 0; j < TN; j++) acc[i][j] = fmaf(av[i], bb[j], acc[i][j]);
    }
  }

#pragma unroll
  for (int i = 0; i < TM; i++) {
    int r = r0 + i;
    if (r < n) {
      __half* o = out + (size_t)r * M + c0;
#pragma unroll
      for (int j = 0; j < TN; j++) o[j] = __float2half(acc[i][j]);
    }
  }
}

// ---------------- Aggregation: fp16 gathers, fp32 accumulate ----------------

__device__ __forceinline__ void h4_fma(uint2 u, float nrm, float4& acc) {
  __half2 h0 = *(__half2*)&u.x, h1 = *(__half2*)&u.y;
  float2 f0 = __half22float2(h0), f1 = __half22float2(h1);
  acc.x = fmaf(f0.x, nrm, acc.x);
  acc.y = fmaf(f0.y, nrm, acc.y);
  acc.z = fmaf(f1.x, nrm, acc.z);
  acc.w = fmaf(f1.y, nrm, acc.w);
}

// M=64: 4 edge-slots x 16 lanes x 4 halves (8B). Row gather = 128B (2 lines).
__global__ __launch_bounds__(256) void agg64_kernel(
    const uint2* __restrict__ xw2, const float* __restrict__ dinv,
    const int2* __restrict__ csr, const int* __restrict__ offs,
    const float* __restrict__ bias, uint2* __restrict__ out2, int n, int etot) {
  int lane = threadIdx.x & 63, wv = threadIdx.x >> 6;
  int slot = lane >> 4, fl = lane & 15;
  int i = blockIdx.x * (TPB / 64) + wv;
  if (i >= n) return;
  int beg = offs[i];
  int end = (i + 1 < n) ? offs[i + 1] : etot;
  float di = dinv[i];
  float4 acc = {0.f, 0.f, 0.f, 0.f};
  if (slot == 0) {  // self-loop (outer di applied in epilogue)
    h4_fma(xw2[(size_t)i * 16 + fl], di, acc);
  }
  int e = beg + slot;
  // unroll-4: 4 independent row-gathers in flight per slot
  for (; e + 12 < end; e += 16) {
    int2 a0 = csr[e];
    int2 a1 = csr[e + 4];
    int2 a2 = csr[e + 8];
    int2 a3 = csr[e + 12];
    uint2 u0 = xw2[(size_t)a0.x * 16 + fl];
    uint2 u1 = xw2[(size_t)a1.x * 16 + fl];
    uint2 u2 = xw2[(size_t)a2.x * 16 + fl];
    uint2 u3 = xw2[(size_t)a3.x * 16 + fl];
    h4_fma(u0, __int_as_float(a0.y), acc);
    h4_fma(u1, __int_as_float(a1.y), acc);
    h4_fma(u2, __int_as_float(a2.y), acc);
    h4_fma(u3, __int_as_float(a3.y), acc);
  }
  for (; e < end; e += 4) {
    int2 er = csr[e];
    h4_fma(xw2[(size_t)er.x * 16 + fl], __int_as_float(er.y), acc);
  }
#pragma unroll
  for (int d = 16; d <= 32; d <<= 1) {
    acc.x += __shfl_xor(acc.x, d);
    acc.y += __shfl_xor(acc.y, d);
    acc.z += __shfl_xor(acc.z, d);
    acc.w += __shfl_xor(acc.w, d);
  }
  if (lane < 16) {
    const float4* b4 = (const float4*)bias;
    float4 b = b4[fl];
    float4 o;
    o.x = fmaxf(acc.x * di + b.x, 0.f);  // both fp16-out layers have ReLU
    o.y = fmaxf(acc.y * di + b.y, 0.f);
    o.z = fmaxf(acc.z * di + b.z, 0.f);
    o.w = fmaxf(acc.w * di + b.w, 0.f);
    __half2 h0 = __float22half2_rn(make_float2(o.x, o.y));
    __half2 h1 = __float22half2_rn(make_float2(o.z, o.w));
    uint2 u;
    u.x = *(unsigned*)&h0;
    u.y = *(unsigned*)&h1;
    out2[(size_t)i * 16 + fl] = u;
  }
}

// M=40: 6 edge-slots x 10 lanes x 4 halves; fp32 output (final layer).
__global__ __launch_bounds__(256) void agg40_kernel(
    const uint2* __restrict__ xw2, const float* __restrict__ dinv,
    const int2* __restrict__ csr, const int* __restrict__ offs,
    const float* __restrict__ bias, float4* __restrict__ out4, int n, int etot) {
  int lane = threadIdx.x & 63, wv = threadIdx.x >> 6;
  int slot = lane / 10, fl = lane % 10;
  int i = blockIdx.x * (TPB / 64) + wv;
  if (i >= n) return;
  int beg = offs[i];
  int end = (i + 1 < n) ? offs[i + 1] : etot;
  float di = dinv[i];
  if (slot >= 6) { beg = 0; end = 0; fl = 0; }
  float4 acc = {0.f, 0.f, 0.f, 0.f};
  if (slot == 0) {
    h4_fma(xw2[(size_t)i * 10 + fl], di, acc);
  }
  int e = beg + slot;
  for (; e + 6 < end; e += 12) {
    int2 a0 = csr[e];
    int2 a1 = csr[e + 6];
    uint2 u0 = xw2[(size_t)a0.x * 10 + fl];
    uint2 u1 = xw2[(size_t)a1.x * 10 + fl];
    h4_fma(u0, __int_as_float(a0.y), acc);
    h4_fma(u1, __int_as_float(a1.y), acc);
  }
  for (; e < end; e += 6) {
    int2 er = csr[e];
    h4_fma(xw2[(size_t)er.x * 10 + fl], __int_as_float(er.y), acc);
  }
  {
    float ax = __shfl(acc.x, lane + 30), ay = __shfl(acc.y, lane + 30);
    float az = __shfl(acc.z, lane + 30), aw = __shfl(acc.w, lane + 30);
    acc.x += ax; acc.y += ay; acc.z += az; acc.w += aw;
  }
  {
    float ax1 = __shfl(acc.x, lane + 10), ax2 = __shfl(acc.x, lane + 20);
    float ay1 = __shfl(acc.y, lane + 10), ay2 = __shfl(acc.y, lane + 20);
    float az1 = __shfl(acc.z, lane + 10), az2 = __shfl(acc.z, lane + 20);
    float aw1 = __shfl(acc.w, lane + 10), aw2 = __shfl(acc.w, lane + 20);
    acc.x += ax1 + ax2; acc.y += ay1 + ay2;
    acc.z += az1 + az2; acc.w += aw1 + aw2;
  }
  if (lane < 10) {
    const float4* b4 = (const float4*)bias;
    float4 b = b4[fl];
    float4 o;
    o.x = acc.x * di + b.x;
    o.y = acc.y * di + b.y;
    o.z = acc.z * di + b.z;
    o.w = acc.w * di + b.w;
    out4[(size_t)i * 10 + fl] = o;
  }
}

// ---------------- launcher ----------------

extern "C" void kernel_launch(void* const* d_in, const int* in_sizes, int n_in,
                              void* d_out, int out_size, void* d_ws, size_t ws_size,
                              hipStream_t stream) {
  const float* x  = (const float*)d_in[0];
  const int*   ei = (const int*)d_in[1];
  const float* W1 = (const float*)d_in[2];
  const float* b1 = (const float*)d_in[3];
  const float* W2 = (const float*)d_in[4];
  const float* b2 = (const float*)d_in[5];
  const float* W3 = (const float*)d_in[6];
  const float* b3 = (const float*)d_in[7];

  int n = in_sizes[0] / 128;
  int e = in_sizes[1] / 2;
  const int* rowA = ei;      // edge_index[0] = source
  const int* colA = ei + e;  // edge_index[1] = destination (segment id)

  size_t off = 0;
  auto alloc = [&](size_t bytes) {
    void* p = (char*)d_ws + off;
    off += (bytes + 255) & ~(size_t)255;
    return p;
  };
  // buffers kept at fp32 sizes (bufA also aliases the binned edge array)
  __half* bufA = (__half*)alloc((size_t)n * 64 * 4);
  __half* bufB = (__half*)alloc((size_t)n * 64 * 4);
  int*   offs  = (int*)alloc((size_t)n * 4);
  float* dinv  = (float*)alloc((size_t)n * 4);
  int2*  csr   = (int2*)alloc((size_t)e * 8);
  int*   bcnt  = (int*)alloc(512 * 4);
  int*   bbase = (int*)alloc(513 * 4);
  int*   bcur  = (int*)alloc(512 * 4);
  int2*  binned = (int2*)bufA;  // consumed by place_kernel before gemm1 writes bufA
  (void)ws_size; (void)n_in; (void)out_size;

  int nb = (n + BD - 1) >> SH;        // buckets (<= 512)
  int nch = (e + CHUNK - 1) / CHUNK;  // binning blocks

  hipMemsetAsync(bcnt, 0, 512 * 4, stream);
  hist_kernel<<<nch, TPB, 0, stream>>>(colA, bcnt, e, nb);
  bscan_kernel<<<1, 64, 0, stream>>>(bcnt, bbase, bcur, nb);
  bin_kernel<<<nch, TPB, 0, stream>>>(rowA, colA, bcur, binned, e, nb);
  fine_count_kernel<<<nb, 512, 0, stream>>>(binned, bbase, offs, dinv, n);
  place_kernel<<<nb, 512, 0, stream>>>(binned, bbase, offs, dinv, csr, n);

  int ggemm = (n + 127) / 128;
  int gagg = (n + 3) / 4;  // one wave per node, 4 waves/block
  gemm_f32in_kernel<128, 64, 8><<<ggemm, TPB, 0, stream>>>(x, W1, bufA, n);
  agg64_kernel<<<gagg, TPB, 0, stream>>>((const uint2*)bufA, dinv, csr, offs,
                                         b1, (uint2*)bufB, n, e);
  gemm_f16in_kernel<64, 64, 8><<<ggemm, TPB, 0, stream>>>(bufB, W2, bufA, n);
  agg64_kernel<<<gagg, TPB, 0, stream>>>((const uint2*)bufA, dinv, csr, offs,
                                         b2, (uint2*)bufB, n, e);
  gemm_f16in_kernel<64, 40, 5><<<ggemm, TPB, 0, stream>>>(bufB, W3, bufA, n);
  agg40_kernel<<<gagg, TPB, 0, stream>>>((const uint2*)bufA, dinv, csr, offs,
                                         b3, (float4*)d_out, n, e);
}

// Round 8
// 381.163 us; speedup vs baseline: 2.4253x; 1.0411x over previous
//
#include <hip/hip_runtime.h>
#include <hip/hip_fp16.h>

constexpr int TPB = 256;
constexpr int SH = 9;          // bucket = 512 consecutive destinations
constexpr int BD = 1 << SH;    // 512 dests per bucket (max 512 buckets -> n <= 262144)
constexpr int CHUNK = 4096;    // edges per binning block

__device__ __forceinline__ int wave_incl_scan(int x, int lane) {
#pragma unroll
  for (int d = 1; d < 64; d <<= 1) {
    int y = __shfl_up(x, d);
    if (lane >= d) x += y;
  }
  return x;
}

// ---------------- binned CSR build (grouped by destination) ----------------

__global__ void hist_kernel(const int* __restrict__ col, int* __restrict__ bcnt,
                            int e, int nb) {
  __shared__ int h[512];
  for (int i = threadIdx.x; i < nb; i += TPB) h[i] = 0;
  __syncthreads();
  int base = blockIdx.x * CHUNK;
  int lim = min(base + CHUNK, e);
  for (int i = base + threadIdx.x; i < lim; i += TPB)
    atomicAdd(&h[col[i] >> SH], 1);
  __syncthreads();
  for (int i = threadIdx.x; i < nb; i += TPB)
    if (h[i]) atomicAdd(&bcnt[i], h[i]);
}

__global__ void bscan_kernel(const int* __restrict__ bcnt, int* __restrict__ bbase,
                             int* __restrict__ bcur, int nb) {
  int lane = threadIdx.x;  // 64 threads
  int carry = 0;
  for (int b = 0; b < nb; b += 64) {
    int i = b + lane;
    int v = (i < nb) ? bcnt[i] : 0;
    int ps = wave_incl_scan(v, lane);
    int ex = carry + ps - v;
    if (i < nb) { bbase[i] = ex; bcur[i] = ex; }
    carry += __shfl(ps, 63);
  }
  if (lane == 0) bbase[nb] = carry;
}

__global__ void bin_kernel(const int* __restrict__ row, const int* __restrict__ col,
                           int* __restrict__ bcur, int2* __restrict__ binned,
                           int e, int nb) {
  __shared__ int h[512];
  __shared__ int base[512];
  for (int i = threadIdx.x; i < nb; i += TPB) h[i] = 0;
  __syncthreads();
  int cb = blockIdx.x * CHUNK;
  int lim = min(cb + CHUNK, e);
  for (int i = cb + threadIdx.x; i < lim; i += TPB)
    atomicAdd(&h[col[i] >> SH], 1);
  __syncthreads();
  for (int i = threadIdx.x; i < nb; i += TPB) {
    int c = h[i];
    base[i] = c ? atomicAdd(&bcur[i], c) : 0;
    h[i] = 0;  // reuse as local cursor
  }
  __syncthreads();
  for (int i = cb + threadIdx.x; i < lim; i += TPB) {
    int c = col[i];  // L2-hot re-read of this block's own chunk
    int b = c >> SH;
    int p = base[b] + atomicAdd(&h[b], 1);
    binned[p] = make_int2(row[i], c);
  }
}

__global__ __launch_bounds__(512) void fine_count_kernel(
    const int2* __restrict__ binned, const int* __restrict__ bbase,
    int* __restrict__ offs, float* __restrict__ dinv, int n) {
  __shared__ int cnt[BD];
  __shared__ int wsum[8];
  int t = threadIdx.x, lane = t & 63, wv = t >> 6;
  int b = blockIdx.x;
  int c0 = b << SH;
  int ndst = min(BD, n - c0);
  cnt[t] = 0;
  __syncthreads();
  int beg = bbase[b], end = bbase[b + 1];
  for (int i = beg + t; i < end; i += 512)
    atomicAdd(&cnt[binned[i].y - c0], 1);
  __syncthreads();
  int v = cnt[t];
  int ps = wave_incl_scan(v, lane);
  if (lane == 63) wsum[wv] = ps;
  __syncthreads();
  int woff = 0;
#pragma unroll
  for (int w = 0; w < 8; w++) woff += (w < wv) ? wsum[w] : 0;
  int ex = woff + ps - v;
  if (t < ndst) {
    offs[c0 + t] = beg + ex;
    dinv[c0 + t] = rsqrtf(1.0f + (float)v);  // deg = incoming + self-loop
  }
}

__global__ __launch_bounds__(512) void place_kernel(
    const int2* __restrict__ binned, const int* __restrict__ bbase,
    const int* __restrict__ offs, const float* __restrict__ dinv,
    int2* __restrict__ csr, int n) {
  __shared__ int cur[BD];
  int t = threadIdx.x;
  int b = blockIdx.x;
  int c0 = b << SH;
  int ndst = min(BD, n - c0);
  cur[t] = (t < ndst) ? offs[c0 + t] : 0;
  __syncthreads();
  int beg = bbase[b], end = bbase[b + 1];
  for (int i = beg + t; i < end; i += 512) {
    int2 rc = binned[i];
    int p = atomicAdd(&cur[rc.y - c0], 1);
    csr[p] = make_int2(rc.x, __float_as_int(dinv[rc.x]));
  }
}

// ---------------- GEMM: register-tiled, fp16 output (fp32 accumulate) ----------------

template <int K, int M, int TN>
__global__ __launch_bounds__(256) void gemm_f32in_kernel(const float* __restrict__ x,
                                                         const float* __restrict__ W,
                                                         __half* __restrict__ out, int n) {
  constexpr int KC = 32;
  constexpr int RB = 128;
  constexpr int RP = RB + 1;
  constexpr int TM = 4;
  __shared__ float xs[KC * RP];
  __shared__ float Ws[K * M];
  int t = threadIdx.x;
  int rg = t & 31, cg = t >> 5;
  int row0 = blockIdx.x * RB;
  int r0 = row0 + rg * TM;
  int c0 = cg * TN;

#pragma unroll
  for (int i = t * 4; i < K * M; i += TPB * 4) *(float4*)&Ws[i] = *(const float4*)&W[i];

  float acc[TM][TN];
#pragma unroll
  for (int i = 0; i < TM; i++)
#pragma unroll
    for (int j = 0; j < TN; j++) acc[i][j] = 0.f;

#pragma unroll 1
  for (int k0 = 0; k0 < K; k0 += KC) {
    __syncthreads();
#pragma unroll
    for (int j = 0; j < (RB * KC) / (TPB * 4); j++) {
      int li = t + TPB * j;
      int row = li / (KC / 4);
      int k4 = li % (KC / 4);
      int rgl = row0 + row;
      if (rgl >= n) rgl = n - 1;
      float4 v = *(const float4*)(x + (size_t)rgl * K + k0 + k4 * 4);
      xs[(k4 * 4 + 0) * RP + row] = v.x;
      xs[(k4 * 4 + 1) * RP + row] = v.y;
      xs[(k4 * 4 + 2) * RP + row] = v.z;
      xs[(k4 * 4 + 3) * RP + row] = v.w;
    }
    __syncthreads();
#pragma unroll
    for (int kk = 0; kk < KC; kk++) {
      float4 a = *(const float4*)&xs[kk * RP + rg * TM];
      float bb[TN];
#pragma unroll
      for (int j = 0; j < TN; j++) bb[j] = Ws[(k0 + kk) * M + c0 + j];
      float av[TM] = {a.x, a.y, a.z, a.w};
#pragma unroll
      for (int i = 0; i < TM; i++)
#pragma unroll
        for (int j = 0; j < TN; j++) acc[i][j] = fmaf(av[i], bb[j], acc[i][j]);
    }
  }

#pragma unroll
  for (int i = 0; i < TM; i++) {
    int r = r0 + i;
    if (r < n) {
      __half* o = out + (size_t)r * M + c0;
#pragma unroll
      for (int j = 0; j < TN; j++) o[j] = __float2half(acc[i][j]);
    }
  }
}

template <int K, int M, int TN>
__global__ __launch_bounds__(256) void gemm_f16in_kernel(const __half* __restrict__ x,
                                                         const float* __restrict__ W,
                                                         __half* __restrict__ out, int n) {
  constexpr int KC = 32;
  constexpr int RB = 128;
  constexpr int RP = RB + 1;
  constexpr int TM = 4;
  __shared__ float xs[KC * RP];
  __shared__ float Ws[K * M];
  int t = threadIdx.x;
  int rg = t & 31, cg = t >> 5;
  int row0 = blockIdx.x * RB;
  int r0 = row0 + rg * TM;
  int c0 = cg * TN;

#pragma unroll
  for (int i = t * 4; i < K * M; i += TPB * 4) *(float4*)&Ws[i] = *(const float4*)&W[i];

  float acc[TM][TN];
#pragma unroll
  for (int i = 0; i < TM; i++)
#pragma unroll
    for (int j = 0; j < TN; j++) acc[i][j] = 0.f;

#pragma unroll 1
  for (int k0 = 0; k0 < K; k0 += KC) {
    __syncthreads();
#pragma unroll
    for (int j = 0; j < (RB * KC) / (TPB * 8); j++) {
      int li = t + TPB * j;
      int row = li / (KC / 8);
      int k8 = li % (KC / 8);
      int rgl = row0 + row;
      if (rgl >= n) rgl = n - 1;
      union { uint4 u; __half2 h[4]; } cv;
      cv.u = *(const uint4*)(x + (size_t)rgl * K + k0 + k8 * 8);
#pragma unroll
      for (int p = 0; p < 4; p++) {
        float2 f = __half22float2(cv.h[p]);
        xs[(k8 * 8 + p * 2 + 0) * RP + row] = f.x;
        xs[(k8 * 8 + p * 2 + 1) * RP + row] = f.y;
      }
    }
    __syncthreads();
#pragma unroll
    for (int kk = 0; kk < KC; kk++) {
      float4 a = *(const float4*)&xs[kk * RP + rg * TM];
      float bb[TN];
#pragma unroll
      for (int j = 0; j < TN; j++) bb[j] = Ws[(k0 + kk) * M + c0 + j];
      float av[TM] = {a.x, a.y, a.z, a.w};
#pragma unroll
      for (int i = 0; i < TM; i++)
#pragma unroll
        for (int j = 0; j < TN; j++) acc[i][j] = fmaf(av[i], bb[j], acc[i][j]);
    }
  }

#pragma unroll
  for (int i = 0; i < TM; i++) {
    int r = r0 + i;
    if (r < n) {
      __half* o = out + (size_t)r * M + c0;
#pragma unroll
      for (int j = 0; j < TN; j++) o[j] = __float2half(acc[i][j]);
    }
  }
}

// ---------------- Aggregation: node-per-slot, batched coalesced edge loads ----------------

__device__ __forceinline__ void h4_fma(uint2 u, float nrm, float4& acc) {
  __half2 h0 = *(__half2*)&u.x, h1 = *(__half2*)&u.y;
  float2 f0 = __half22float2(h0), f1 = __half22float2(h1);
  acc.x = fmaf(f0.x, nrm, acc.x);
  acc.y = fmaf(f0.y, nrm, acc.y);
  acc.z = fmaf(f1.x, nrm, acc.z);
  acc.w = fmaf(f1.y, nrm, acc.w);
}

// M=64: slot (16 lanes) owns one node; 4 nodes/wave. Per batch: 16 csr records
// loaded coalesced (one 128B line per slot), shfl-broadcast within slot, then up
// to 16 independent 128B row-gathers hoisted before the FMA chain.
__global__ __launch_bounds__(256) void agg64_kernel(
    const uint2* __restrict__ xw2, const float* __restrict__ dinv,
    const int2* __restrict__ csr, const int* __restrict__ offs,
    const float* __restrict__ bias, uint2* __restrict__ out2, int n, int etot) {
  int lane = threadIdx.x & 63, wv = threadIdx.x >> 6;
  int slot = lane >> 4, fl = lane & 15;
  int sb = slot << 4;  // slot's base lane
  int i = blockIdx.x * 16 + wv * 4 + slot;
  bool valid = i < n;
  int ic = valid ? i : n - 1;
  int beg = offs[ic];
  int end = (ic + 1 < n) ? offs[ic + 1] : etot;
  if (!valid) end = beg;
  float di = dinv[ic];
  float4 acc = {0.f, 0.f, 0.f, 0.f};
  // self-loop (outer di applied in epilogue); independent of edge chain
  h4_fma(xw2[(size_t)ic * 16 + fl], di, acc);

  for (int b = beg; b < end; b += 16) {
    int2 er = csr[min(b + fl, etot - 1)];  // coalesced 128B batch per slot
    int cnt = end - b;                     // slot-uniform
    uint2 u[16];
    // issue all gathers first (independent -> deep MLP)
#pragma unroll
    for (int j = 0; j < 16; j++) {
      if (j < cnt) {
        int r = __shfl(er.x, sb + j);
        u[j] = xw2[(size_t)r * 16 + fl];
      }
    }
#pragma unroll
    for (int j = 0; j < 16; j++) {
      if (j < cnt) {
        float nrm = __int_as_float(__shfl(er.y, sb + j));
        h4_fma(u[j], nrm, acc);
      }
    }
  }

  if (valid) {
    const float4* b4 = (const float4*)bias;
    float4 bb = b4[fl];
    float4 o;
    o.x = fmaxf(acc.x * di + bb.x, 0.f);  // both fp16-out layers have ReLU
    o.y = fmaxf(acc.y * di + bb.y, 0.f);
    o.z = fmaxf(acc.z * di + bb.z, 0.f);
    o.w = fmaxf(acc.w * di + bb.w, 0.f);
    __half2 h0 = __float22half2_rn(make_float2(o.x, o.y));
    __half2 h1 = __float22half2_rn(make_float2(o.z, o.w));
    uint2 u;
    u.x = *(unsigned*)&h0;
    u.y = *(unsigned*)&h1;
    out2[(size_t)i * 16 + fl] = u;
  }
}

// M=40: same structure; 10 active feature lanes per slot, all 16 lanes help
// load the csr batch. fp32 output (final layer, no ReLU).
__global__ __launch_bounds__(256) void agg40_kernel(
    const uint2* __restrict__ xw2, const float* __restrict__ dinv,
    const int2* __restrict__ csr, const int* __restrict__ offs,
    const float* __restrict__ bias, float4* __restrict__ out4, int n, int etot) {
  int lane = threadIdx.x & 63, wv = threadIdx.x >> 6;
  int slot = lane >> 4, fl = lane & 15;
  int sb = slot << 4;
  bool flv = fl < 10;
  int flc = flv ? fl : 0;
  int i = blockIdx.x * 16 + wv * 4 + slot;
  bool valid = i < n;
  int ic = valid ? i : n - 1;
  int beg = offs[ic];
  int end = (ic + 1 < n) ? offs[ic + 1] : etot;
  if (!valid) end = beg;
  float di = dinv[ic];
  float4 acc = {0.f, 0.f, 0.f, 0.f};
  h4_fma(xw2[(size_t)ic * 10 + flc], di, acc);

  for (int b = beg; b < end; b += 16) {
    int2 er = csr[min(b + fl, etot - 1)];
    int cnt = end - b;
    uint2 u[16];
#pragma unroll
    for (int j = 0; j < 16; j++) {
      if (j < cnt) {
        int r = __shfl(er.x, sb + j);
        u[j] = xw2[(size_t)r * 10 + flc];
      }
    }
#pragma unroll
    for (int j = 0; j < 16; j++) {
      if (j < cnt) {
        float nrm = __int_as_float(__shfl(er.y, sb + j));
        h4_fma(u[j], nrm, acc);
      }
    }
  }

  if (valid && flv) {
    const float4* b4 = (const float4*)bias;
    float4 bb = b4[fl];
    float4 o;
    o.x = acc.x * di + bb.x;
    o.y = acc.y * di + bb.y;
    o.z = acc.z * di + bb.z;
    o.w = acc.w * di + bb.w;
    out4[(size_t)i * 10 + fl] = o;
  }
}

// ---------------- launcher ----------------

extern "C" void kernel_launch(void* const* d_in, const int* in_sizes, int n_in,
                              void* d_out, int out_size, void* d_ws, size_t ws_size,
                              hipStream_t stream) {
  const float* x  = (const float*)d_in[0];
  const int*   ei = (const int*)d_in[1];
  const float* W1 = (const float*)d_in[2];
  const float* b1 = (const float*)d_in[3];
  const float* W2 = (const float*)d_in[4];
  const float* b2 = (const float*)d_in[5];
  const float* W3 = (const float*)d_in[6];
  const float* b3 = (const float*)d_in[7];

  int n = in_sizes[0] / 128;
  int e = in_sizes[1] / 2;
  const int* rowA = ei;      // edge_index[0] = source
  const int* colA = ei + e;  // edge_index[1] = destination (segment id)

  size_t off = 0;
  auto alloc = [&](size_t bytes) {
    void* p = (char*)d_ws + off;
    off += (bytes + 255) & ~(size_t)255;
    return p;
  };
  // buffers kept at fp32 sizes (bufA also aliases the binned edge array)
  __half* bufA = (__half*)alloc((size_t)n * 64 * 4);
  __half* bufB = (__half*)alloc((size_t)n * 64 * 4);
  int*   offs  = (int*)alloc((size_t)n * 4);
  float* dinv  = (float*)alloc((size_t)n * 4);
  int2*  csr   = (int2*)alloc((size_t)e * 8);
  int*   bcnt  = (int*)alloc(512 * 4);
  int*   bbase = (int*)alloc(513 * 4);
  int*   bcur  = (int*)alloc(512 * 4);
  int2*  binned = (int2*)bufA;  // consumed by place_kernel before gemm1 writes bufA
  (void)ws_size; (void)n_in; (void)out_size;

  int nb = (n + BD - 1) >> SH;        // buckets (<= 512)
  int nch = (e + CHUNK - 1) / CHUNK;  // binning blocks

  hipMemsetAsync(bcnt, 0, 512 * 4, stream);
  hist_kernel<<<nch, TPB, 0, stream>>>(colA, bcnt, e, nb);
  bscan_kernel<<<1, 64, 0, stream>>>(bcnt, bbase, bcur, nb);
  bin_kernel<<<nch, TPB, 0, stream>>>(rowA, colA, bcur, binned, e, nb);
  fine_count_kernel<<<nb, 512, 0, stream>>>(binned, bbase, offs, dinv, n);
  place_kernel<<<nb, 512, 0, stream>>>(binned, bbase, offs, dinv, csr, n);

  int ggemm = (n + 127) / 128;
  int gagg = (n + 15) / 16;  // 4 nodes per wave, 4 waves/block
  gemm_f32in_kernel<128, 64, 8><<<ggemm, TPB, 0, stream>>>(x, W1, bufA, n);
  agg64_kernel<<<gagg, TPB, 0, stream>>>((const uint2*)bufA, dinv, csr, offs,
                                         b1, (uint2*)bufB, n, e);
  gemm_f16in_kernel<64, 64, 8><<<ggemm, TPB, 0, stream>>>(bufB, W2, bufA, n);
  agg64_kernel<<<gagg, TPB, 0, stream>>>((const uint2*)bufA, dinv, csr, offs,
                                         b2, (uint2*)bufB, n, e);
  gemm_f16in_kernel<64, 40, 5><<<ggemm, TPB, 0, stream>>>(bufB, W3, bufA, n);
  agg40_kernel<<<gagg, TPB, 0, stream>>>((const uint2*)bufA, dinv, csr, offs,
                                         b3, (float4*)d_out, n, e);
}

// Round 9
// 340.296 us; speedup vs baseline: 2.7165x; 1.1201x over previous
//
#include <hip/hip_runtime.h>
#include <hip/hip_fp16.h>

constexpr int TPB = 256;
constexpr int SH = 9;          // bucket = 512 consecutive destinations
constexpr int BD = 1 << SH;    // 512 dests per bucket (max 512 buckets -> n <= 262144)
constexpr int CHUNK = 4096;    // edges per binning block

typedef _Float16 half8 __attribute__((ext_vector_type(8)));
typedef float float4v __attribute__((ext_vector_type(4)));

__device__ __forceinline__ int wave_incl_scan(int x, int lane) {
#pragma unroll
  for (int d = 1; d < 64; d <<= 1) {
    int y = __shfl_up(x, d);
    if (lane >= d) x += y;
  }
  return x;
}

// ---------------- binned CSR build (grouped by destination) ----------------

__global__ void hist_kernel(const int* __restrict__ col, int* __restrict__ bcnt,
                            int e, int nb) {
  __shared__ int h[512];
  for (int i = threadIdx.x; i < nb; i += TPB) h[i] = 0;
  __syncthreads();
  int base = blockIdx.x * CHUNK;
  int lim = min(base + CHUNK, e);
  for (int i = base + threadIdx.x; i < lim; i += TPB)
    atomicAdd(&h[col[i] >> SH], 1);
  __syncthreads();
  for (int i = threadIdx.x; i < nb; i += TPB)
    if (h[i]) atomicAdd(&bcnt[i], h[i]);
}

__global__ void bscan_kernel(const int* __restrict__ bcnt, int* __restrict__ bbase,
                             int* __restrict__ bcur, int nb) {
  int lane = threadIdx.x;  // 64 threads
  int carry = 0;
  for (int b = 0; b < nb; b += 64) {
    int i = b + lane;
    int v = (i < nb) ? bcnt[i] : 0;
    int ps = wave_incl_scan(v, lane);
    int ex = carry + ps - v;
    if (i < nb) { bbase[i] = ex; bcur[i] = ex; }
    carry += __shfl(ps, 63);
  }
  if (lane == 0) bbase[nb] = carry;
}

__global__ void bin_kernel(const int* __restrict__ row, const int* __restrict__ col,
                           int* __restrict__ bcur, int2* __restrict__ binned,
                           int e, int nb) {
  __shared__ int h[512];
  __shared__ int base[512];
  for (int i = threadIdx.x; i < nb; i += TPB) h[i] = 0;
  __syncthreads();
  int cb = blockIdx.x * CHUNK;
  int lim = min(cb + CHUNK, e);
  for (int i = cb + threadIdx.x; i < lim; i += TPB)
    atomicAdd(&h[col[i] >> SH], 1);
  __syncthreads();
  for (int i = threadIdx.x; i < nb; i += TPB) {
    int c = h[i];
    base[i] = c ? atomicAdd(&bcur[i], c) : 0;
    h[i] = 0;  // reuse as local cursor
  }
  __syncthreads();
  for (int i = cb + threadIdx.x; i < lim; i += TPB) {
    int c = col[i];  // L2-hot re-read of this block's own chunk
    int b = c >> SH;
    int p = base[b] + atomicAdd(&h[b], 1);
    binned[p] = make_int2(row[i], c);
  }
}

__global__ __launch_bounds__(512) void fine_count_kernel(
    const int2* __restrict__ binned, const int* __restrict__ bbase,
    int* __restrict__ offs, float* __restrict__ dinv, int n) {
  __shared__ int cnt[BD];
  __shared__ int wsum[8];
  int t = threadIdx.x, lane = t & 63, wv = t >> 6;
  int b = blockIdx.x;
  int c0 = b << SH;
  int ndst = min(BD, n - c0);
  cnt[t] = 0;
  __syncthreads();
  int beg = bbase[b], end = bbase[b + 1];
  for (int i = beg + t; i < end; i += 512)
    atomicAdd(&cnt[binned[i].y - c0], 1);
  __syncthreads();
  int v = cnt[t];
  int ps = wave_incl_scan(v, lane);
  if (lane == 63) wsum[wv] = ps;
  __syncthreads();
  int woff = 0;
#pragma unroll
  for (int w = 0; w < 8; w++) woff += (w < wv) ? wsum[w] : 0;
  int ex = woff + ps - v;
  if (t < ndst) {
    offs[c0 + t] = beg + ex;
    dinv[c0 + t] = rsqrtf(1.0f + (float)v);  // deg = incoming + self-loop
  }
}

__global__ __launch_bounds__(512) void place_kernel(
    const int2* __restrict__ binned, const int* __restrict__ bbase,
    const int* __restrict__ offs, const float* __restrict__ dinv,
    int2* __restrict__ csr, int n) {
  __shared__ int cur[BD];
  int t = threadIdx.x;
  int b = blockIdx.x;
  int c0 = b << SH;
  int ndst = min(BD, n - c0);
  cur[t] = (t < ndst) ? offs[c0 + t] : 0;
  __syncthreads();
  int beg = bbase[b], end = bbase[b + 1];
  for (int i = beg + t; i < end; i += 512) {
    int2 rc = binned[i];
    int p = atomicAdd(&cur[rc.y - c0], 1);
    csr[p] = make_int2(rc.x, __float_as_int(dinv[rc.x]));
  }
}

// ---------------- MFMA GEMM (fp16 in, fp32 acc, fp16 out; no LDS) ----------------

// Pack W[K,M] fp32 into B-fragment order for mfma_f32_16x16x32_f16:
// frag f = ct*KT+kt; within frag: lane holds B[k=kt*32+(lane>>4)*8+j][n=ct*16+(lane&15)].
template <int K, int M, int CT, int KT>
__global__ void pack_w_kernel(const float* __restrict__ W, _Float16* __restrict__ P) {
  int idx = blockIdx.x * TPB + threadIdx.x;
  if (idx >= CT * KT * 64 * 8) return;
  int j = idx & 7;
  int lane = (idx >> 3) & 63;
  int f = idx >> 9;
  int kt = f % KT, ct = f / KT;
  int c = ct * 16 + (lane & 15);
  int k = kt * 32 + (lane >> 4) * 8 + j;
  float v = (c < M) ? W[k * M + c] : 0.f;
  P[idx] = (_Float16)v;
}

// layer-1: fp32 x[n,K] -> fp16 out[n,M]. 4 waves/block, 16 rows/wave.
template <int K, int M, int CT>
__global__ __launch_bounds__(256) void gemm_mfma_f32in(const float* __restrict__ x,
                                                       const _Float16* __restrict__ PW,
                                                       _Float16* __restrict__ out, int n) {
  constexpr int KT = K / 32;
  int lane = threadIdx.x & 63, wv = threadIdx.x >> 6;
  int m = lane & 15, q = lane >> 4;
  int row0w = blockIdx.x * 64 + wv * 16;
  int arow = row0w + m;
  int ar = arow < n ? arow : n - 1;  // clamp; stores are guarded
  const half8* pw = (const half8*)PW;

  float4v acc[CT];
#pragma unroll
  for (int ct = 0; ct < CT; ct++) acc[ct] = (float4v){0.f, 0.f, 0.f, 0.f};

#pragma unroll
  for (int kt = 0; kt < KT; kt++) {
    const float* xp = x + (size_t)ar * K + kt * 32 + q * 8;
    float4 x0 = *(const float4*)xp;
    float4 x1 = *(const float4*)(xp + 4);
    half8 a;
    a[0] = (_Float16)x0.x; a[1] = (_Float16)x0.y;
    a[2] = (_Float16)x0.z; a[3] = (_Float16)x0.w;
    a[4] = (_Float16)x1.x; a[5] = (_Float16)x1.y;
    a[6] = (_Float16)x1.z; a[7] = (_Float16)x1.w;
#pragma unroll
    for (int ct = 0; ct < CT; ct++) {
      half8 b = pw[(ct * KT + kt) * 64 + lane];
      acc[ct] = __builtin_amdgcn_mfma_f32_16x16x32_f16(a, b, acc[ct], 0, 0, 0);
    }
  }
  // D layout: col = lane&15, row = q*4 + reg
  int r0 = row0w + q * 4;
#pragma unroll
  for (int ct = 0; ct < CT; ct++) {
    int c = ct * 16 + m;
    if (c < M) {
#pragma unroll
      for (int reg = 0; reg < 4; reg++) {
        int r = r0 + reg;
        if (r < n) out[(size_t)r * M + c] = (_Float16)acc[ct][reg];
      }
    }
  }
}

// layers 2/3: fp16 x[n,K] -> fp16 out[n,M]
template <int K, int M, int CT>
__global__ __launch_bounds__(256) void gemm_mfma_f16in(const _Float16* __restrict__ x,
                                                       const _Float16* __restrict__ PW,
                                                       _Float16* __restrict__ out, int n) {
  constexpr int KT = K / 32;
  int lane = threadIdx.x & 63, wv = threadIdx.x >> 6;
  int m = lane & 15, q = lane >> 4;
  int row0w = blockIdx.x * 64 + wv * 16;
  int arow = row0w + m;
  int ar = arow < n ? arow : n - 1;
  const half8* pw = (const half8*)PW;

  float4v acc[CT];
#pragma unroll
  for (int ct = 0; ct < CT; ct++) acc[ct] = (float4v){0.f, 0.f, 0.f, 0.f};

#pragma unroll
  for (int kt = 0; kt < KT; kt++) {
    half8 a = *(const half8*)(x + (size_t)ar * K + kt * 32 + q * 8);
#pragma unroll
    for (int ct = 0; ct < CT; ct++) {
      half8 b = pw[(ct * KT + kt) * 64 + lane];
      acc[ct] = __builtin_amdgcn_mfma_f32_16x16x32_f16(a, b, acc[ct], 0, 0, 0);
    }
  }
  int r0 = row0w + q * 4;
#pragma unroll
  for (int ct = 0; ct < CT; ct++) {
    int c = ct * 16 + m;
    if (c < M) {
#pragma unroll
      for (int reg = 0; reg < 4; reg++) {
        int r = r0 + reg;
        if (r < n) out[(size_t)r * M + c] = (_Float16)acc[ct][reg];
      }
    }
  }
}

// ---------------- Aggregation: node-per-slot, batched coalesced edge loads ----------------

__device__ __forceinline__ void h4_fma(uint2 u, float nrm, float4& acc) {
  __half2 h0 = *(__half2*)&u.x, h1 = *(__half2*)&u.y;
  float2 f0 = __half22float2(h0), f1 = __half22float2(h1);
  acc.x = fmaf(f0.x, nrm, acc.x);
  acc.y = fmaf(f0.y, nrm, acc.y);
  acc.z = fmaf(f1.x, nrm, acc.z);
  acc.w = fmaf(f1.y, nrm, acc.w);
}

// M=64: slot (16 lanes) owns one node; 4 nodes/wave.
__global__ __launch_bounds__(256) void agg64_kernel(
    const uint2* __restrict__ xw2, const float* __restrict__ dinv,
    const int2* __restrict__ csr, const int* __restrict__ offs,
    const float* __restrict__ bias, uint2* __restrict__ out2, int n, int etot) {
  int lane = threadIdx.x & 63, wv = threadIdx.x >> 6;
  int slot = lane >> 4, fl = lane & 15;
  int sb = slot << 4;  // slot's base lane
  int i = blockIdx.x * 16 + wv * 4 + slot;
  bool valid = i < n;
  int ic = valid ? i : n - 1;
  int beg = offs[ic];
  int end = (ic + 1 < n) ? offs[ic + 1] : etot;
  if (!valid) end = beg;
  float di = dinv[ic];
  float4 acc = {0.f, 0.f, 0.f, 0.f};
  h4_fma(xw2[(size_t)ic * 16 + fl], di, acc);  // self-loop

  for (int b = beg; b < end; b += 16) {
    int2 er = csr[min(b + fl, etot - 1)];  // coalesced 128B batch per slot
    int cnt = end - b;                     // slot-uniform
    uint2 u[16];
#pragma unroll
    for (int j = 0; j < 16; j++) {
      if (j < cnt) {
        int r = __shfl(er.x, sb + j);
        u[j] = xw2[(size_t)r * 16 + fl];
      }
    }
#pragma unroll
    for (int j = 0; j < 16; j++) {
      if (j < cnt) {
        float nrm = __int_as_float(__shfl(er.y, sb + j));
        h4_fma(u[j], nrm, acc);
      }
    }
  }

  if (valid) {
    const float4* b4 = (const float4*)bias;
    float4 bb = b4[fl];
    float4 o;
    o.x = fmaxf(acc.x * di + bb.x, 0.f);  // both fp16-out layers have ReLU
    o.y = fmaxf(acc.y * di + bb.y, 0.f);
    o.z = fmaxf(acc.z * di + bb.z, 0.f);
    o.w = fmaxf(acc.w * di + bb.w, 0.f);
    __half2 h0 = __float22half2_rn(make_float2(o.x, o.y));
    __half2 h1 = __float22half2_rn(make_float2(o.z, o.w));
    uint2 u;
    u.x = *(unsigned*)&h0;
    u.y = *(unsigned*)&h1;
    out2[(size_t)i * 16 + fl] = u;
  }
}

// M=40: same structure; 10 active feature lanes/slot; fp32 output (final layer).
__global__ __launch_bounds__(256) void agg40_kernel(
    const uint2* __restrict__ xw2, const float* __restrict__ dinv,
    const int2* __restrict__ csr, const int* __restrict__ offs,
    const float* __restrict__ bias, float4* __restrict__ out4, int n, int etot) {
  int lane = threadIdx.x & 63, wv = threadIdx.x >> 6;
  int slot = lane >> 4, fl = lane & 15;
  int sb = slot << 4;
  bool flv = fl < 10;
  int flc = flv ? fl : 0;
  int i = blockIdx.x * 16 + wv * 4 + slot;
  bool valid = i < n;
  int ic = valid ? i : n - 1;
  int beg = offs[ic];
  int end = (ic + 1 < n) ? offs[ic + 1] : etot;
  if (!valid) end = beg;
  float di = dinv[ic];
  float4 acc = {0.f, 0.f, 0.f, 0.f};
  h4_fma(xw2[(size_t)ic * 10 + flc], di, acc);

  for (int b = beg; b < end; b += 16) {
    int2 er = csr[min(b + fl, etot - 1)];
    int cnt = end - b;
    uint2 u[16];
#pragma unroll
    for (int j = 0; j < 16; j++) {
      if (j < cnt) {
        int r = __shfl(er.x, sb + j);
        u[j] = xw2[(size_t)r * 10 + flc];
      }
    }
#pragma unroll
    for (int j = 0; j < 16; j++) {
      if (j < cnt) {
        float nrm = __int_as_float(__shfl(er.y, sb + j));
        h4_fma(u[j], nrm, acc);
      }
    }
  }

  if (valid && flv) {
    const float4* b4 = (const float4*)bias;
    float4 bb = b4[fl];
    float4 o;
    o.x = acc.x * di + bb.x;
    o.y = acc.y * di + bb.y;
    o.z = acc.z * di + bb.z;
    o.w = acc.w * di + bb.w;
    out4[(size_t)i * 10 + fl] = o;
  }
}

// ---------------- launcher ----------------

extern "C" void kernel_launch(void* const* d_in, const int* in_sizes, int n_in,
                              void* d_out, int out_size, void* d_ws, size_t ws_size,
                              hipStream_t stream) {
  const float* x  = (const float*)d_in[0];
  const int*   ei = (const int*)d_in[1];
  const float* W1 = (const float*)d_in[2];
  const float* b1 = (const float*)d_in[3];
  const float* W2 = (const float*)d_in[4];
  const float* b2 = (const float*)d_in[5];
  const float* W3 = (const float*)d_in[6];
  const float* b3 = (const float*)d_in[7];

  int n = in_sizes[0] / 128;
  int e = in_sizes[1] / 2;
  const int* rowA = ei;      // edge_index[0] = source
  const int* colA = ei + e;  // edge_index[1] = destination (segment id)

  size_t off = 0;
  auto alloc = [&](size_t bytes) {
    void* p = (char*)d_ws + off;
    off += (bytes + 255) & ~(size_t)255;
    return p;
  };
  // bufA kept at n*64*4 bytes: also aliases the binned edge array (e*8 <= n*256)
  __half* bufA = (__half*)alloc((size_t)n * 64 * 4);
  __half* bufB = (__half*)alloc((size_t)n * 64 * 4);
  int*   offs  = (int*)alloc((size_t)n * 4);
  float* dinv  = (float*)alloc((size_t)n * 4);
  int2*  csr   = (int2*)alloc((size_t)e * 8);
  int*   bcnt  = (int*)alloc(512 * 4);
  int*   bbase = (int*)alloc(513 * 4);
  int*   bcur  = (int*)alloc(512 * 4);
  _Float16* PW1 = (_Float16*)alloc(4 * 4 * 64 * 8 * 2);  // CT=4, KT=4
  _Float16* PW2 = (_Float16*)alloc(4 * 2 * 64 * 8 * 2);  // CT=4, KT=2
  _Float16* PW3 = (_Float16*)alloc(3 * 2 * 64 * 8 * 2);  // CT=3, KT=2
  int2*  binned = (int2*)bufA;  // consumed by place_kernel before gemm1 writes bufA
  (void)ws_size; (void)n_in; (void)out_size;

  int nb = (n + BD - 1) >> SH;        // buckets (<= 512)
  int nch = (e + CHUNK - 1) / CHUNK;  // binning blocks

  hipMemsetAsync(bcnt, 0, 512 * 4, stream);
  hist_kernel<<<nch, TPB, 0, stream>>>(colA, bcnt, e, nb);
  bscan_kernel<<<1, 64, 0, stream>>>(bcnt, bbase, bcur, nb);
  bin_kernel<<<nch, TPB, 0, stream>>>(rowA, colA, bcur, binned, e, nb);
  fine_count_kernel<<<nb, 512, 0, stream>>>(binned, bbase, offs, dinv, n);
  place_kernel<<<nb, 512, 0, stream>>>(binned, bbase, offs, dinv, csr, n);

  pack_w_kernel<128, 64, 4, 4><<<(4 * 4 * 512 + TPB - 1) / TPB, TPB, 0, stream>>>(W1, PW1);
  pack_w_kernel<64, 64, 4, 2><<<(4 * 2 * 512 + TPB - 1) / TPB, TPB, 0, stream>>>(W2, PW2);
  pack_w_kernel<64, 40, 3, 2><<<(3 * 2 * 512 + TPB - 1) / TPB, TPB, 0, stream>>>(W3, PW3);

  int gmf = (n + 63) / 64;   // 4 waves/block, 16 rows/wave
  int gagg = (n + 15) / 16;  // 4 nodes per wave, 4 waves/block
  gemm_mfma_f32in<128, 64, 4><<<gmf, TPB, 0, stream>>>(x, PW1, (_Float16*)bufA, n);
  agg64_kernel<<<gagg, TPB, 0, stream>>>((const uint2*)bufA, dinv, csr, offs,
                                         b1, (uint2*)bufB, n, e);
  gemm_mfma_f16in<64, 64, 4><<<gmf, TPB, 0, stream>>>((const _Float16*)bufB, PW2,
                                                      (_Float16*)bufA, n);
  agg64_kernel<<<gagg, TPB, 0, stream>>>((const uint2*)bufA, dinv, csr, offs,
                                         b2, (uint2*)bufB, n, e);
  gemm_mfma_f16in<64, 40, 3><<<gmf, TPB, 0, stream>>>((const _Float16*)bufB, PW3,
                                                      (_Float16*)bufA, n);
  agg40_kernel<<<gagg, TPB, 0, stream>>>((const uint2*)bufA, dinv, csr, offs,
                                         b3, (float4*)d_out, n, e);
}

// Round 10
// 273.369 us; speedup vs baseline: 3.3816x; 1.2448x over previous
//
#include <hip/hip_runtime.h>
#include <hip/hip_fp16.h>

constexpr int TPB = 256;
constexpr int SH = 9;          // bucket = 512 consecutive destinations
constexpr int BD = 1 << SH;    // 512 dests per bucket (max 512 buckets -> n <= 262144)
constexpr int CHUNK = 4096;    // edges per binning block

typedef _Float16 half8 __attribute__((ext_vector_type(8)));
typedef float float4v __attribute__((ext_vector_type(4)));

__device__ __forceinline__ int wave_incl_scan(int x, int lane) {
#pragma unroll
  for (int d = 1; d < 64; d <<= 1) {
    int y = __shfl_up(x, d);
    if (lane >= d) x += y;
  }
  return x;
}

// ---------------- binned CSR build (grouped by destination) ----------------
// Buckets have fixed capacity `cap` (mean + 25%, >25-sigma for uniform-random
// edges) so no global scan is needed: bucket b occupies [b*cap, b*cap+count).

__global__ void bin_kernel(const int* __restrict__ row, const int* __restrict__ col,
                           int* __restrict__ bcur, int2* __restrict__ binned,
                           int e, int nb, int cap) {
  __shared__ int h[512];
  __shared__ int base[512];
  for (int i = threadIdx.x; i < nb; i += TPB) h[i] = 0;
  __syncthreads();
  int cb = blockIdx.x * CHUNK;
  int lim = min(cb + CHUNK, e);
  for (int i = cb + threadIdx.x; i < lim; i += TPB)
    atomicAdd(&h[col[i] >> SH], 1);
  __syncthreads();
  for (int i = threadIdx.x; i < nb; i += TPB) {
    int c = h[i];
    base[i] = c ? (i * cap + atomicAdd(&bcur[i], c)) : 0;
    h[i] = 0;  // reuse as local cursor
  }
  __syncthreads();
  for (int i = cb + threadIdx.x; i < lim; i += TPB) {
    int c = col[i];  // L2-hot re-read of this block's own chunk
    int b = c >> SH;
    int p = base[b] + atomicAdd(&h[b], 1);
    binned[p] = make_int2(row[i], c);
  }
}

// per bucket: fine counts -> scan -> offs2/dinv -> place (fused; binned stays L2-hot)
__global__ __launch_bounds__(512) void count_place_kernel(
    const int2* __restrict__ binned, const int* __restrict__ bcnt, int cap,
    int2* __restrict__ offs2, float* __restrict__ dinv, int* __restrict__ csr, int n) {
  __shared__ int cnt[BD];
  __shared__ int wsum[8];
  int t = threadIdx.x, lane = t & 63, wv = t >> 6;
  int b = blockIdx.x;
  int c0 = b << SH;
  int ndst = min(BD, n - c0);
  cnt[t] = 0;
  __syncthreads();
  int beg = b * cap;
  int end = beg + bcnt[b];
  for (int i = beg + t; i < end; i += 512)
    atomicAdd(&cnt[binned[i].y - c0], 1);
  __syncthreads();
  int v = cnt[t];
  int ps = wave_incl_scan(v, lane);
  if (lane == 63) wsum[wv] = ps;
  __syncthreads();
  int woff = 0;
#pragma unroll
  for (int w = 0; w < 8; w++) woff += (w < wv) ? wsum[w] : 0;
  int ex = woff + ps - v;
  if (t < ndst) {
    offs2[c0 + t] = make_int2(beg + ex, beg + ex + v);
    dinv[c0 + t] = rsqrtf(1.0f + (float)v);  // deg = incoming + self-loop
  }
  __syncthreads();  // counts consumed; reuse cnt[] as cursors
  cnt[t] = beg + ex;
  __syncthreads();
  for (int i = beg + t; i < end; i += 512) {
    int2 rc = binned[i];
    int p = atomicAdd(&cnt[rc.y - c0], 1);
    csr[p] = rc.x;
  }
}

// ---------------- MFMA GEMM (fp16 in, fp32 acc; no LDS) ----------------

// Pack W[K,M] fp32 into B-fragment order for mfma_f32_16x16x32_f16:
// frag f = ct*KT+kt; lane holds B[k=kt*32+(lane>>4)*8+j][n=ct*16+(lane&15)].
template <int K, int M, int CT, int KT>
__global__ void pack_w_kernel(const float* __restrict__ W, _Float16* __restrict__ P) {
  int idx = blockIdx.x * TPB + threadIdx.x;
  if (idx >= CT * KT * 64 * 8) return;
  int j = idx & 7;
  int lane = (idx >> 3) & 63;
  int f = idx >> 9;
  int kt = f % KT, ct = f / KT;
  int c = ct * 16 + (lane & 15);
  int k = kt * 32 + (lane >> 4) * 8 + j;
  float v = (c < M) ? W[k * M + c] : 0.f;
  P[idx] = (_Float16)v;
}

// layer-1: fp32 x[n,K] -> fp16 out[n,M]. 4 waves/block, 16 rows/wave.
template <int K, int M, int CT>
__global__ __launch_bounds__(256) void gemm_mfma_f32in(const float* __restrict__ x,
                                                       const _Float16* __restrict__ PW,
                                                       _Float16* __restrict__ out, int n) {
  constexpr int KT = K / 32;
  int lane = threadIdx.x & 63, wv = threadIdx.x >> 6;
  int m = lane & 15, q = lane >> 4;
  int row0w = blockIdx.x * 64 + wv * 16;
  int arow = row0w + m;
  int ar = arow < n ? arow : n - 1;  // clamp; stores are guarded
  const half8* pw = (const half8*)PW;

  float4v acc[CT];
#pragma unroll
  for (int ct = 0; ct < CT; ct++) acc[ct] = (float4v){0.f, 0.f, 0.f, 0.f};

#pragma unroll
  for (int kt = 0; kt < KT; kt++) {
    const float* xp = x + (size_t)ar * K + kt * 32 + q * 8;
    float4 x0 = *(const float4*)xp;
    float4 x1 = *(const float4*)(xp + 4);
    half8 a;
    a[0] = (_Float16)x0.x; a[1] = (_Float16)x0.y;
    a[2] = (_Float16)x0.z; a[3] = (_Float16)x0.w;
    a[4] = (_Float16)x1.x; a[5] = (_Float16)x1.y;
    a[6] = (_Float16)x1.z; a[7] = (_Float16)x1.w;
#pragma unroll
    for (int ct = 0; ct < CT; ct++) {
      half8 b = pw[(ct * KT + kt) * 64 + lane];
      acc[ct] = __builtin_amdgcn_mfma_f32_16x16x32_f16(a, b, acc[ct], 0, 0, 0);
    }
  }
  // D layout: col = lane&15, row = q*4 + reg
  int r0 = row0w + q * 4;
#pragma unroll
  for (int ct = 0; ct < CT; ct++) {
    int c = ct * 16 + m;
    if (c < M) {
#pragma unroll
      for (int reg = 0; reg < 4; reg++) {
        int r = r0 + reg;
        if (r < n) out[(size_t)r * M + c] = (_Float16)acc[ct][reg];
      }
    }
  }
}

// layer-2: fp16 x[n,K] -> fp16 out[n,M]
template <int K, int M, int CT>
__global__ __launch_bounds__(256) void gemm_mfma_f16in(const _Float16* __restrict__ x,
                                                       const _Float16* __restrict__ PW,
                                                       _Float16* __restrict__ out, int n) {
  constexpr int KT = K / 32;
  int lane = threadIdx.x & 63, wv = threadIdx.x >> 6;
  int m = lane & 15, q = lane >> 4;
  int row0w = blockIdx.x * 64 + wv * 16;
  int arow = row0w + m;
  int ar = arow < n ? arow : n - 1;
  const half8* pw = (const half8*)PW;

  float4v acc[CT];
#pragma unroll
  for (int ct = 0; ct < CT; ct++) acc[ct] = (float4v){0.f, 0.f, 0.f, 0.f};

#pragma unroll
  for (int kt = 0; kt < KT; kt++) {
    half8 a = *(const half8*)(x + (size_t)ar * K + kt * 32 + q * 8);
#pragma unroll
    for (int ct = 0; ct < CT; ct++) {
      half8 b = pw[(ct * KT + kt) * 64 + lane];
      acc[ct] = __builtin_amdgcn_mfma_f32_16x16x32_f16(a, b, acc[ct], 0, 0, 0);
    }
  }
  int r0 = row0w + q * 4;
#pragma unroll
  for (int ct = 0; ct < CT; ct++) {
    int c = ct * 16 + m;
    if (c < M) {
#pragma unroll
      for (int reg = 0; reg < 4; reg++) {
        int r = r0 + reg;
        if (r < n) out[(size_t)r * M + c] = (_Float16)acc[ct][reg];
      }
    }
  }
}

// layer-3: fp16 x[n,K] -> fp32 out[n,M] with fused bias (no relu)
template <int K, int M, int CT>
__global__ __launch_bounds__(256) void gemm_mfma_f16in_f32out(
    const _Float16* __restrict__ x, const _Float16* __restrict__ PW,
    const float* __restrict__ bias, float* __restrict__ out, int n) {
  constexpr int KT = K / 32;
  int lane = threadIdx.x & 63, wv = threadIdx.x >> 6;
  int m = lane & 15, q = lane >> 4;
  int row0w = blockIdx.x * 64 + wv * 16;
  int arow = row0w + m;
  int ar = arow < n ? arow : n - 1;
  const half8* pw = (const half8*)PW;

  float4v acc[CT];
#pragma unroll
  for (int ct = 0; ct < CT; ct++) acc[ct] = (float4v){0.f, 0.f, 0.f, 0.f};

#pragma unroll
  for (int kt = 0; kt < KT; kt++) {
    half8 a = *(const half8*)(x + (size_t)ar * K + kt * 32 + q * 8);
#pragma unroll
    for (int ct = 0; ct < CT; ct++) {
      half8 b = pw[(ct * KT + kt) * 64 + lane];
      acc[ct] = __builtin_amdgcn_mfma_f32_16x16x32_f16(a, b, acc[ct], 0, 0, 0);
    }
  }
  int r0 = row0w + q * 4;
#pragma unroll
  for (int ct = 0; ct < CT; ct++) {
    int c = ct * 16 + m;
    if (c < M) {
      float bb = bias[c];
#pragma unroll
      for (int reg = 0; reg < 4; reg++) {
        int r = r0 + reg;
        if (r < n) out[(size_t)r * M + c] = acc[ct][reg] + bb;
      }
    }
  }
}

// ---------------- Aggregation: node-per-slot, batched coalesced edge loads ----------------

__device__ __forceinline__ void h4_fma(uint2 u, float nrm, float4& acc) {
  __half2 h0 = *(__half2*)&u.x, h1 = *(__half2*)&u.y;
  float2 f0 = __half22float2(h0), f1 = __half22float2(h1);
  acc.x = fmaf(f0.x, nrm, acc.x);
  acc.y = fmaf(f0.y, nrm, acc.y);
  acc.z = fmaf(f1.x, nrm, acc.z);
  acc.w = fmaf(f1.y, nrm, acc.w);
}

// Slot (16 lanes) owns one node; 4 nodes/wave. Per batch: 16 csr ints loaded
// coalesced (64B/slot), per-lane dinv lookup (L2-hot 400KB), shfl-broadcast,
// then up to 16 independent 128B row-gathers hoisted before the FMA chain.
// RELU_BIAS: bias+relu+fp16 epilogue (layers 1/2); else pure L(h) fp16 (layer-3 pre-agg).
template <bool RELU_BIAS>
__global__ __launch_bounds__(256) void agg64_kernel(
    const uint2* __restrict__ xw2, const float* __restrict__ dinv,
    const int* __restrict__ csr, const int2* __restrict__ offs2,
    const float* __restrict__ bias, uint2* __restrict__ out2, int n) {
  int lane = threadIdx.x & 63, wv = threadIdx.x >> 6;
  int slot = lane >> 4, fl = lane & 15;
  int sb = slot << 4;  // slot's base lane
  int i = blockIdx.x * 16 + wv * 4 + slot;
  bool valid = i < n;
  int ic = valid ? i : n - 1;
  int2 oe = offs2[ic];
  int beg = oe.x;
  int end = valid ? oe.y : beg;
  float di = dinv[ic];
  float4 acc = {0.f, 0.f, 0.f, 0.f};
  h4_fma(xw2[(size_t)ic * 16 + fl], di, acc);  // self-loop (outer di in epilogue)

  for (int b = beg; b < end; b += 16) {
    int idx = b + fl;
    int rr = 0;
    float dd = 0.f;
    if (idx < end) {  // csr slack holds poison; predicate the loads
      rr = csr[idx];
      dd = dinv[rr];
    }
    int cnt = end - b;  // slot-uniform
    uint2 u[16];
#pragma unroll
    for (int j = 0; j < 16; j++) {
      if (j < cnt) {
        int r = __shfl(rr, sb + j);
        u[j] = xw2[(size_t)r * 16 + fl];
      }
    }
#pragma unroll
    for (int j = 0; j < 16; j++) {
      if (j < cnt) {
        float nrm = __shfl(dd, sb + j);
        h4_fma(u[j], nrm, acc);
      }
    }
  }

  if (valid) {
    float4 o;
    if (RELU_BIAS) {
      const float4* b4 = (const float4*)bias;
      float4 bb = b4[fl];
      o.x = fmaxf(acc.x * di + bb.x, 0.f);
      o.y = fmaxf(acc.y * di + bb.y, 0.f);
      o.z = fmaxf(acc.z * di + bb.z, 0.f);
      o.w = fmaxf(acc.w * di + bb.w, 0.f);
    } else {
      o.x = acc.x * di; o.y = acc.y * di;
      o.z = acc.z * di; o.w = acc.w * di;
    }
    __half2 h0 = __float22half2_rn(make_float2(o.x, o.y));
    __half2 h1 = __float22half2_rn(make_float2(o.z, o.w));
    uint2 u;
    u.x = *(unsigned*)&h0;
    u.y = *(unsigned*)&h1;
    out2[(size_t)i * 16 + fl] = u;
  }
}

// ---------------- launcher ----------------

extern "C" void kernel_launch(void* const* d_in, const int* in_sizes, int n_in,
                              void* d_out, int out_size, void* d_ws, size_t ws_size,
                              hipStream_t stream) {
  const float* x  = (const float*)d_in[0];
  const int*   ei = (const int*)d_in[1];
  const float* W1 = (const float*)d_in[2];
  const float* b1 = (const float*)d_in[3];
  const float* W2 = (const float*)d_in[4];
  const float* b2 = (const float*)d_in[5];
  const float* W3 = (const float*)d_in[6];
  const float* b3 = (const float*)d_in[7];

  int n = in_sizes[0] / 128;
  int e = in_sizes[1] / 2;
  const int* rowA = ei;      // edge_index[0] = source
  const int* colA = ei + e;  // edge_index[1] = destination (segment id)

  int nb = (n + BD - 1) >> SH;  // buckets (<= 512)
  int meanb = e / nb;
  int cap = meanb + (meanb / 4 > 1024 ? meanb / 4 : 1024);  // >25 sigma slack
  int nch = (e + CHUNK - 1) / CHUNK;

  size_t off = 0;
  auto alloc = [&](size_t bytes) {
    void* p = (char*)d_ws + off;
    off += (bytes + 255) & ~(size_t)255;
    return p;
  };
  // bufA (n*64*4 B) also aliases the binned edge array (nb*cap*8 <= n*205 B)
  __half* bufA  = (__half*)alloc((size_t)n * 64 * 4);
  __half* bufB  = (__half*)alloc((size_t)n * 64 * 4);
  int2*  offs2  = (int2*)alloc((size_t)n * 8);
  float* dinv   = (float*)alloc((size_t)n * 4);
  int*   csr    = (int*)alloc((size_t)nb * cap * 4);
  int*   bcur   = (int*)alloc(512 * 4);
  _Float16* PW1 = (_Float16*)alloc(4 * 4 * 64 * 8 * 2);  // CT=4, KT=4
  _Float16* PW2 = (_Float16*)alloc(4 * 2 * 64 * 8 * 2);  // CT=4, KT=2
  _Float16* PW3 = (_Float16*)alloc(3 * 2 * 64 * 8 * 2);  // CT=3, KT=2
  int2*  binned = (int2*)bufA;  // consumed by count_place before gemm1 writes bufA
  (void)ws_size; (void)n_in; (void)out_size;

  hipMemsetAsync(bcur, 0, (size_t)nb * 4, stream);
  bin_kernel<<<nch, TPB, 0, stream>>>(rowA, colA, bcur, binned, e, nb, cap);
  count_place_kernel<<<nb, 512, 0, stream>>>(binned, bcur, cap, offs2, dinv, csr, n);

  pack_w_kernel<128, 64, 4, 4><<<(4 * 4 * 512 + TPB - 1) / TPB, TPB, 0, stream>>>(W1, PW1);
  pack_w_kernel<64, 64, 4, 2><<<(4 * 2 * 512 + TPB - 1) / TPB, TPB, 0, stream>>>(W2, PW2);
  pack_w_kernel<64, 40, 3, 2><<<(3 * 2 * 512 + TPB - 1) / TPB, TPB, 0, stream>>>(W3, PW3);

  int gmf = (n + 63) / 64;   // 4 waves/block, 16 rows/wave
  int gagg = (n + 15) / 16;  // 4 nodes per wave, 4 waves/block
  gemm_mfma_f32in<128, 64, 4><<<gmf, TPB, 0, stream>>>(x, PW1, (_Float16*)bufA, n);
  agg64_kernel<true><<<gagg, TPB, 0, stream>>>((const uint2*)bufA, dinv, csr, offs2,
                                               b1, (uint2*)bufB, n);
  gemm_mfma_f16in<64, 64, 4><<<gmf, TPB, 0, stream>>>((const _Float16*)bufB, PW2,
                                                      (_Float16*)bufA, n);
  agg64_kernel<true><<<gagg, TPB, 0, stream>>>((const uint2*)bufA, dinv, csr, offs2,
                                               b2, (uint2*)bufB, n);
  // layer 3: aggregate-first (L(h2)), then GEMM with fused bias -> fp32 d_out
  agg64_kernel<false><<<gagg, TPB, 0, stream>>>((const uint2*)bufB, dinv, csr, offs2,
                                                nullptr, (uint2*)bufA, n);
  gemm_mfma_f16in_f32out<64, 40, 3><<<gmf, TPB, 0, stream>>>((const _Float16*)bufA, PW3,
                                                             b3, (float*)d_out, n);
}